// Round 1
// baseline (680.895 us; speedup 1.0000x reference)
//
#include <hip/hip_runtime.h>
#include <math.h>

#define NATOMS 1536
#define NSPEC 8
#define HID 64
#define NCEN 32
#define CUTOFF_R 5.0f
#define PI_F 3.14159265358979323846f

__device__ __forceinline__ float silu_f(float x) {
    return x / (1.f + __expf(-x));
}

// ---------------------------------------------------------------------------
// K1: per-atom block. Neighbor scan over all j:
//   - accumulate species-bucketed RBF basis into LDS (local features)
//   - append in-cutoff (i<j) pairs to global compacted list (ballot-aggregated)
//   - run charge MLP 289->64->64->1 for this atom, write raw[i]
// ---------------------------------------------------------------------------
__global__ __launch_bounds__(256) void k_local(
    const int* __restrict__ species, const float* __restrict__ pos,
    const float* __restrict__ tq, const float* __restrict__ embed,
    const float* __restrict__ cW1, const float* __restrict__ cb1,
    const float* __restrict__ cW2, const float* __restrict__ cb2,
    const float* __restrict__ cW3, const float* __restrict__ cb3,
    const float* __restrict__ charge_scale,
    float* __restrict__ raw, unsigned int* __restrict__ pcount,
    unsigned int* __restrict__ plist)
{
    __shared__ float s_local[NSPEC * NCEN];   // 256 floats, c-major [species][center]
    __shared__ float s_pre[64];
    __shared__ float s_h[64];
    const int i = blockIdx.x;
    const int t = threadIdx.x;
    const int lane = t & 63;
    s_local[t] = 0.f;
    __syncthreads();

    const float xi = pos[3*i+0], yi = pos[3*i+1], zi = pos[3*i+2];
    const int si = species[i];

    for (int j0 = 0; j0 < NATOMS; j0 += 256) {
        const int j = j0 + t;
        const float dx = xi - pos[3*j+0];
        const float dy = yi - pos[3*j+1];
        const float dz = zi - pos[3*j+2];
        const float d = sqrtf(dx*dx + dy*dy + dz*dz + 1e-12f);
        const bool within = (d < CUTOFF_R);
        if (within && j != i) {
            const float cut = 0.5f * (__cosf((PI_F / CUTOFF_R) * d) + 1.f);
            float* dst = &s_local[species[j] * NCEN];
            #pragma unroll
            for (int k = 0; k < NCEN; k++) {
                const float diff = d - (float)k * (CUTOFF_R / 31.f);
                atomicAdd(&dst[k], __expf(-4.f * diff * diff) * cut);
            }
        }
        // compacted pair list append (i < j, within cutoff)
        const bool app = within && (j > i);
        const unsigned long long mask = __ballot((int)app);
        if (mask) {
            const int leader = (int)__ffsll(mask) - 1;
            unsigned base = 0;
            if (lane == leader) base = atomicAdd(pcount, (unsigned)__popcll(mask));
            base = __shfl(base, leader);
            if (app) {
                const unsigned ofs = base + (unsigned)__popcll(mask & ((1ull << lane) - 1ull));
                plist[ofs] = ((unsigned)i << 16) | (unsigned)j;
            }
        }
    }
    __syncthreads();

    // ---- charge MLP: x = [s_local(256), embed[si](32), Q(1)] ----
    const float Q = tq[0];
    if (t < 64) s_pre[t] = cb1[t];
    __syncthreads();
    {   // layer 1: 289 -> 64, 4 wave-chunks over k
        const int g = t >> 6, o = t & 63;
        const int k0 = g * 73;
        const int k1 = (g == 3) ? 289 : (k0 + 73);
        float acc = 0.f;
        for (int k = k0; k < k1; k++) {
            float xv;
            if (k < 256)      xv = s_local[k];
            else if (k < 288) xv = embed[si * 32 + (k - 256)];
            else              xv = Q;
            acc += xv * cW1[k * 64 + o];
        }
        atomicAdd(&s_pre[o], acc);
    }
    __syncthreads();
    if (t < 64) s_h[t] = silu_f(s_pre[t]);
    __syncthreads();
    if (t < 64) s_pre[t] = cb2[t];
    __syncthreads();
    {   // layer 2: 64 -> 64
        const int g = t >> 6, o = t & 63;
        float acc = 0.f;
        #pragma unroll
        for (int kk = 0; kk < 16; kk++) {
            const int k = g * 16 + kk;
            acc += s_h[k] * cW2[k * 64 + o];
        }
        atomicAdd(&s_pre[o], acc);
    }
    __syncthreads();
    if (t < 64) {   // layer 3: 64 -> 1, wave reduce
        float v = silu_f(s_pre[t]) * cW3[t];
        #pragma unroll
        for (int off = 32; off > 0; off >>= 1) v += __shfl_down(v, off);
        if (t == 0) raw[i] = (v + cb3[0]) * charge_scale[0];
    }
}

// ---------------------------------------------------------------------------
// K2: charges = raw - mean(raw) + Q/N   (single block)
// ---------------------------------------------------------------------------
__global__ __launch_bounds__(256) void k_charges(
    const float* __restrict__ raw, const float* __restrict__ tq,
    float* __restrict__ charges)
{
    __shared__ float s_red[256];
    const int t = threadIdx.x;
    float acc = 0.f;
    for (int idx = t; idx < NATOMS; idx += 256) acc += raw[idx];
    s_red[t] = acc;
    __syncthreads();
    for (int s = 128; s > 0; s >>= 1) { if (t < s) s_red[t] += s_red[t + s]; __syncthreads(); }
    const float mean = s_red[0] / (float)NATOMS;
    const float add = tq[0] / (float)NATOMS;
    for (int idx = t; idx < NATOMS; idx += 256) charges[idx] = raw[idx] - mean + add;
}

// ---------------------------------------------------------------------------
// K3: long-range Coulomb over ALL ordered pairs i<j (no cutoff)
// ---------------------------------------------------------------------------
__global__ __launch_bounds__(256) void k_lr(
    const float* __restrict__ pos, const float* __restrict__ charges,
    const float* __restrict__ softening, double* __restrict__ e_lr)
{
    __shared__ float s_red[256];
    const int i = blockIdx.y;
    const int t = threadIdx.x;
    const int j = blockIdx.x * 256 + t;
    float term = 0.f;
    if (j > i) {
        const float dx = pos[3*i+0] - pos[3*j+0];
        const float dy = pos[3*i+1] - pos[3*j+1];
        const float dz = pos[3*i+2] - pos[3*j+2];
        const float d2 = dx*dx + dy*dy + dz*dz + 1e-12f;
        const float sr = softening[0];
        const float sp = ((sr > 20.f) ? sr : log1pf(expf(sr))) + 0.001f;
        term = charges[i] * charges[j] * rsqrtf(d2 + sp * sp);
    }
    s_red[t] = term;
    __syncthreads();
    for (int s = 128; s > 0; s >>= 1) { if (t < s) s_red[t] += s_red[t + s]; __syncthreads(); }
    if (t == 0 && s_red[0] != 0.f) atomicAdd(e_lr, (double)s_red[0]);
}

// ---------------------------------------------------------------------------
// K4: dense pair MLP over the compacted in-cutoff pair list.
// Weights staged in LDS (W1 transposed so inner loop is contiguous,
// wave-uniform -> broadcast ds_read_b128). Layer-2 accumulators interleaved
// with layer-1 production so only feat[96]+acc2[64] live in registers.
// ---------------------------------------------------------------------------
__global__ __launch_bounds__(256) void k_pair(
    const int* __restrict__ species, const float* __restrict__ pos,
    const float* __restrict__ embed,
    const float* __restrict__ W1, const float* __restrict__ b1,
    const float* __restrict__ W2, const float* __restrict__ b2,
    const float* __restrict__ W3, const float* __restrict__ b3,
    const unsigned int* __restrict__ pcount, const unsigned int* __restrict__ plist,
    double* __restrict__ e_pair)
{
    __shared__ float s_w1t[HID * 96];  // [o][m] = W1[m][o]  (24 KB)
    __shared__ float s_w2[HID * HID];  // original [k][o]    (16 KB)
    __shared__ float s_w3[HID];
    __shared__ float s_b1[HID];
    __shared__ float s_b2[HID];
    __shared__ float s_red[256];
    const int t = threadIdx.x;

    for (int idx = t; idx < HID * 96; idx += 256) {
        const int o = idx / 96, m = idx - o * 96;
        s_w1t[idx] = W1[m * HID + o];
    }
    for (int idx = t; idx < HID * HID; idx += 256) s_w2[idx] = W2[idx];
    if (t < HID) { s_w3[t] = W3[t]; s_b1[t] = b1[t]; s_b2[t] = b2[t]; }
    __syncthreads();

    const float b3v = b3[0];
    const unsigned cnt = *pcount;
    const float4* __restrict__ e4 = (const float4*)embed;
    float esum = 0.f;

    for (unsigned p = blockIdx.x * 256u + (unsigned)t; p < cnt; p += gridDim.x * 256u) {
        const unsigned pk = plist[p];
        const int i = (int)(pk >> 16), j = (int)(pk & 0xffffu);
        const float dx = pos[3*i+0] - pos[3*j+0];
        const float dy = pos[3*i+1] - pos[3*j+1];
        const float dz = pos[3*i+2] - pos[3*j+2];
        const float d = sqrtf(dx*dx + dy*dy + dz*dz + 1e-12f);
        const float cut = 0.5f * (__cosf((PI_F / CUTOFF_R) * d) + 1.f);

        float feat[96];
        #pragma unroll
        for (int m = 0; m < NCEN; m++) {
            const float diff = d - (float)m * (CUTOFF_R / 31.f);
            feat[m] = __expf(-4.f * diff * diff);
        }
        const int si8 = species[i] * 8, sj8 = species[j] * 8;
        #pragma unroll
        for (int q = 0; q < 8; q++) {
            const float4 a = e4[si8 + q];
            const float4 b = e4[sj8 + q];
            feat[32 + 4*q + 0] = a.x + b.x;  feat[64 + 4*q + 0] = a.x * b.x;
            feat[32 + 4*q + 1] = a.y + b.y;  feat[64 + 4*q + 1] = a.y * b.y;
            feat[32 + 4*q + 2] = a.z + b.z;  feat[64 + 4*q + 2] = a.z * b.z;
            feat[32 + 4*q + 3] = a.w + b.w;  feat[64 + 4*q + 3] = a.w * b.w;
        }

        float acc2[HID];
        #pragma unroll
        for (int o = 0; o < HID; o++) acc2[o] = s_b2[o];

        #pragma unroll 1
        for (int k = 0; k < HID; k++) {
            float a1 = s_b1[k];
            #pragma unroll
            for (int m = 0; m < 96; m++) a1 += feat[m] * s_w1t[k * 96 + m];
            const float h = silu_f(a1);
            #pragma unroll
            for (int o = 0; o < HID; o++) acc2[o] += h * s_w2[k * HID + o];
        }
        float e = b3v;
        #pragma unroll
        for (int o = 0; o < HID; o++) e += silu_f(acc2[o]) * s_w3[o];
        esum += e * cut;
    }

    s_red[t] = esum;
    __syncthreads();
    for (int s = 128; s > 0; s >>= 1) { if (t < s) s_red[t] += s_red[t + s]; __syncthreads(); }
    if (t == 0 && s_red[0] != 0.f) atomicAdd(e_pair, (double)s_red[0]);
}

// ---------------------------------------------------------------------------
// K5: energy = e_pair + coulomb_scale*e_lr + sum(atom_bias[species])
// ---------------------------------------------------------------------------
__global__ __launch_bounds__(256) void k_final(
    const int* __restrict__ species, const float* __restrict__ atom_bias,
    const float* __restrict__ coulomb_scale,
    const double* __restrict__ e_pair, const double* __restrict__ e_lr,
    float* __restrict__ out_energy)
{
    __shared__ float s_red[256];
    const int t = threadIdx.x;
    float acc = 0.f;
    for (int idx = t; idx < NATOMS; idx += 256) acc += atom_bias[species[idx]];
    s_red[t] = acc;
    __syncthreads();
    for (int s = 128; s > 0; s >>= 1) { if (t < s) s_red[t] += s_red[t + s]; __syncthreads(); }
    if (t == 0) {
        out_energy[0] = (float)(e_pair[0] + (double)coulomb_scale[0] * e_lr[0] + (double)s_red[0]);
    }
}

// ---------------------------------------------------------------------------
extern "C" void kernel_launch(void* const* d_in, const int* in_sizes, int n_in,
                              void* d_out, int out_size, void* d_ws, size_t ws_size,
                              hipStream_t stream) {
    const int*   species       = (const int*)d_in[0];
    const float* pos           = (const float*)d_in[1];
    const float* tq            = (const float*)d_in[2];
    const float* embed         = (const float*)d_in[3];
    const float* W1            = (const float*)d_in[4];
    const float* b1            = (const float*)d_in[5];
    const float* W2            = (const float*)d_in[6];
    const float* b2            = (const float*)d_in[7];
    const float* W3            = (const float*)d_in[8];
    const float* b3            = (const float*)d_in[9];
    const float* atom_bias     = (const float*)d_in[10];
    const float* cW1           = (const float*)d_in[11];
    const float* cb1           = (const float*)d_in[12];
    const float* cW2           = (const float*)d_in[13];
    const float* cb2           = (const float*)d_in[14];
    const float* cW3           = (const float*)d_in[15];
    const float* cb3           = (const float*)d_in[16];
    const float* charge_scale  = (const float*)d_in[17];
    const float* coulomb_scale = (const float*)d_in[18];
    const float* softening     = (const float*)d_in[19];

    char* ws = (char*)d_ws;
    double*   e_pair = (double*)(ws + 0);
    double*   e_lr   = (double*)(ws + 8);
    unsigned* pcount = (unsigned*)(ws + 16);
    float*    raw    = (float*)(ws + 32);
    unsigned* plist  = (unsigned*)(ws + 8192);

    float* out     = (float*)d_out;
    float* charges = out + 1;   // output layout: [energy, charges[1536]]

    hipMemsetAsync(d_ws, 0, 32, stream);  // zero e_pair, e_lr, pcount

    k_local<<<NATOMS, 256, 0, stream>>>(species, pos, tq, embed,
                                        cW1, cb1, cW2, cb2, cW3, cb3,
                                        charge_scale, raw, pcount, plist);
    k_charges<<<1, 256, 0, stream>>>(raw, tq, charges);
    k_lr<<<dim3(NATOMS / 256, NATOMS), 256, 0, stream>>>(pos, charges, softening, e_lr);
    k_pair<<<1024, 256, 0, stream>>>(species, pos, embed,
                                     W1, b1, W2, b2, W3, b3,
                                     pcount, plist, e_pair);
    k_final<<<1, 256, 0, stream>>>(species, atom_bias, coulomb_scale,
                                   e_pair, e_lr, out);
}

// Round 2
// 537.726 us; speedup vs baseline: 1.2662x; 1.2662x over previous
//
#include <hip/hip_runtime.h>
#include <math.h>

#define NATOMS 1536
#define NSPEC 8
#define HID 64
#define NCEN 32
#define CUTOFF_R 5.0f
#define PI_F 3.14159265358979323846f

__device__ __forceinline__ float silu_f(float x) {
    return x / (1.f + __expf(-x));
}

// ---------------------------------------------------------------------------
// K1: per-atom block.
//  Phase 1: scan all j, compact in-cutoff neighbors (d, cut, spec) into LDS
//           list (ballot-aggregated); append i<j pairs to global pair list.
//  Phase 2: thread (g, k=t&31) strides the neighbor list, adds rbf*cut into
//           s_local[spec*32+k] — lane==k spreads atomics across all banks.
//  Phase 3: charge MLP 289->64->64->1, write raw[i].
// ---------------------------------------------------------------------------
__global__ __launch_bounds__(256) void k_local(
    const int* __restrict__ species, const float* __restrict__ pos,
    const float* __restrict__ tq, const float* __restrict__ embed,
    const float* __restrict__ cW1, const float* __restrict__ cb1,
    const float* __restrict__ cW2, const float* __restrict__ cb2,
    const float* __restrict__ cW3, const float* __restrict__ cb3,
    const float* __restrict__ charge_scale,
    float* __restrict__ raw, unsigned int* __restrict__ pcount,
    unsigned int* __restrict__ plist)
{
    __shared__ float s_local[NSPEC * NCEN];   // [species][center]
    __shared__ float d_l[NATOMS];
    __shared__ float c_l[NATOMS];
    __shared__ int   sp_l[NATOMS];
    __shared__ unsigned n_cnt;
    __shared__ float s_pre[64];
    __shared__ float s_h[64];

    const int i = blockIdx.x;
    const int t = threadIdx.x;
    const int lane = t & 63;
    s_local[t] = 0.f;
    if (t == 0) n_cnt = 0u;
    __syncthreads();

    const float xi = pos[3*i+0], yi = pos[3*i+1], zi = pos[3*i+2];
    const int si = species[i];

    // ---- phase 1: neighbor compaction + pair-list append ----
    for (int j0 = 0; j0 < NATOMS; j0 += 256) {
        const int j = j0 + t;
        const float dx = xi - pos[3*j+0];
        const float dy = yi - pos[3*j+1];
        const float dz = zi - pos[3*j+2];
        const float d = sqrtf(dx*dx + dy*dy + dz*dz + 1e-12f);
        const bool within = (d < CUTOFF_R) && (j != i);
        const float cut = 0.5f * (__cosf((PI_F / CUTOFF_R) * d) + 1.f);

        const unsigned long long m = __ballot((int)within);
        if (m) {
            const int leader = (int)__ffsll(m) - 1;
            unsigned base = 0;
            if (lane == leader) base = atomicAdd(&n_cnt, (unsigned)__popcll(m));
            base = (unsigned)__shfl((int)base, leader);
            if (within) {
                const unsigned ofs = base + (unsigned)__popcll(m & ((1ull << lane) - 1ull));
                d_l[ofs] = d; c_l[ofs] = cut; sp_l[ofs] = species[j];
            }
        }
        const bool app = (d < CUTOFF_R) && (j > i);
        const unsigned long long m2 = __ballot((int)app);
        if (m2) {
            const int leader = (int)__ffsll(m2) - 1;
            unsigned base = 0;
            if (lane == leader) base = atomicAdd(pcount, (unsigned)__popcll(m2));
            base = (unsigned)__shfl((int)base, leader);
            if (app) {
                const unsigned ofs = base + (unsigned)__popcll(m2 & ((1ull << lane) - 1ull));
                plist[ofs] = ((unsigned)i << 16) | (unsigned)j;
            }
        }
    }
    __syncthreads();

    // ---- phase 2: dense basis accumulation, bank-spread atomics ----
    {
        const unsigned cnt = n_cnt;
        const int k = t & 31, g = t >> 5;
        const float ck = (float)k * (CUTOFF_R / 31.f);
        for (unsigned n = (unsigned)g; n < cnt; n += 8) {
            const float diff = d_l[n] - ck;
            atomicAdd(&s_local[sp_l[n] * NCEN + k],
                      __expf(-4.f * diff * diff) * c_l[n]);
        }
    }
    __syncthreads();

    // ---- phase 3: charge MLP x = [s_local(256), embed[si](32), Q(1)] ----
    const float Q = tq[0];
    if (t < 64) s_pre[t] = cb1[t];
    __syncthreads();
    {   // layer 1: 289 -> 64
        const int g = t >> 6, o = t & 63;
        const int k0 = g * 73;
        const int k1 = (g == 3) ? 289 : (k0 + 73);
        float acc = 0.f;
        for (int k = k0; k < k1; k++) {
            float xv;
            if (k < 256)      xv = s_local[k];
            else if (k < 288) xv = embed[si * 32 + (k - 256)];
            else              xv = Q;
            acc += xv * cW1[k * 64 + o];
        }
        atomicAdd(&s_pre[o], acc);
    }
    __syncthreads();
    if (t < 64) s_h[t] = silu_f(s_pre[t]);
    __syncthreads();
    if (t < 64) s_pre[t] = cb2[t];
    __syncthreads();
    {   // layer 2: 64 -> 64
        const int g = t >> 6, o = t & 63;
        float acc = 0.f;
        #pragma unroll
        for (int kk = 0; kk < 16; kk++) {
            const int k = g * 16 + kk;
            acc += s_h[k] * cW2[k * 64 + o];
        }
        atomicAdd(&s_pre[o], acc);
    }
    __syncthreads();
    if (t < 64) {   // layer 3: 64 -> 1
        float v = silu_f(s_pre[t]) * cW3[t];
        #pragma unroll
        for (int off = 32; off > 0; off >>= 1) v += __shfl_down(v, off);
        if (t == 0) raw[i] = (v + cb3[0]) * charge_scale[0];
    }
}

// ---------------------------------------------------------------------------
// K2: charges = raw - mean(raw) + Q/N   (single block)
// ---------------------------------------------------------------------------
__global__ __launch_bounds__(256) void k_charges(
    const float* __restrict__ raw, const float* __restrict__ tq,
    float* __restrict__ charges)
{
    __shared__ float s_red[256];
    const int t = threadIdx.x;
    float acc = 0.f;
    for (int idx = t; idx < NATOMS; idx += 256) acc += raw[idx];
    s_red[t] = acc;
    __syncthreads();
    for (int s = 128; s > 0; s >>= 1) { if (t < s) s_red[t] += s_red[t + s]; __syncthreads(); }
    const float mean = s_red[0] / (float)NATOMS;
    const float add = tq[0] / (float)NATOMS;
    for (int idx = t; idx < NATOMS; idx += 256) charges[idx] = raw[idx] - mean + add;
}

// ---------------------------------------------------------------------------
// K3: long-range Coulomb, persistent blocks, per-thread accumulation
// ---------------------------------------------------------------------------
__global__ __launch_bounds__(256) void k_lr(
    const float* __restrict__ pos, const float* __restrict__ charges,
    const float* __restrict__ softening, double* __restrict__ e_lr)
{
    __shared__ float s_red[256];
    const int t = threadIdx.x;
    const float sr = softening[0];
    const float sp = ((sr > 20.f) ? sr : log1pf(__expf(sr))) + 0.001f;
    const float sp2 = sp * sp;
    float acc = 0.f;
    for (int i = blockIdx.x; i < NATOMS; i += gridDim.x) {
        const float xi = pos[3*i+0], yi = pos[3*i+1], zi = pos[3*i+2];
        const float qi = charges[i];
        for (int j = i + 1 + t; j < NATOMS; j += 256) {
            const float dx = xi - pos[3*j+0];
            const float dy = yi - pos[3*j+1];
            const float dz = zi - pos[3*j+2];
            const float d2 = dx*dx + dy*dy + dz*dz + 1e-12f;
            acc += qi * charges[j] * rsqrtf(d2 + sp2);
        }
    }
    s_red[t] = acc;
    __syncthreads();
    for (int s = 128; s > 0; s >>= 1) { if (t < s) s_red[t] += s_red[t + s]; __syncthreads(); }
    if (t == 0 && s_red[0] != 0.f) atomicAdd(e_lr, (double)s_red[0]);
}

// ---------------------------------------------------------------------------
// K4: dense pair MLP over compacted list. Spill-free restructure:
//   layer1 accumulates a1[64] over on-the-fly features (feat[96] never
//   materialized); layers 2+3 fused so only h[64] + one scalar are live.
//   Weights in LDS, wave-uniform broadcast ds_read_b128; W2 pre-transposed.
// ---------------------------------------------------------------------------
__global__ __launch_bounds__(256) void k_pair(
    const int* __restrict__ species, const float* __restrict__ pos,
    const float* __restrict__ embed,
    const float* __restrict__ W1, const float* __restrict__ b1,
    const float* __restrict__ W2, const float* __restrict__ b2,
    const float* __restrict__ W3, const float* __restrict__ b3,
    const unsigned int* __restrict__ pcount, const unsigned int* __restrict__ plist,
    double* __restrict__ e_pair)
{
    __shared__ float s_w1[96 * HID];   // [m][o], contiguous in o (24 KB)
    __shared__ float s_w2t[HID * HID]; // [o][k] = W2[k][o], contiguous in k (16 KB)
    __shared__ float s_w3[HID];
    __shared__ float s_b1[HID];
    __shared__ float s_b2[HID];
    __shared__ float s_red[256];
    const int t = threadIdx.x;

    for (int idx = t; idx < 96 * HID; idx += 256) s_w1[idx] = W1[idx];
    for (int idx = t; idx < HID * HID; idx += 256) {
        const int o = idx >> 6, k = idx & 63;
        s_w2t[idx] = W2[k * HID + o];
    }
    if (t < HID) { s_w3[t] = W3[t]; s_b1[t] = b1[t]; s_b2[t] = b2[t]; }
    __syncthreads();

    const float4* __restrict__ w1v = (const float4*)s_w1;
    const float4* __restrict__ w2v = (const float4*)s_w2t;
    const float4* __restrict__ e4 = (const float4*)embed;
    const float b3v = b3[0];
    const unsigned cnt = *pcount;
    float esum = 0.f;

    for (unsigned p = blockIdx.x * 256u + (unsigned)t; p < cnt; p += gridDim.x * 256u) {
        const unsigned pk = plist[p];
        const int i = (int)(pk >> 16), j = (int)(pk & 0xffffu);
        const float dx = pos[3*i+0] - pos[3*j+0];
        const float dy = pos[3*i+1] - pos[3*j+1];
        const float dz = pos[3*i+2] - pos[3*j+2];
        const float d = sqrtf(dx*dx + dy*dy + dz*dz + 1e-12f);
        const float cut = 0.5f * (__cosf((PI_F / CUTOFF_R) * d) + 1.f);

        float a1[HID];
        #pragma unroll
        for (int o = 0; o < HID; o++) a1[o] = s_b1[o];

        // RBF rows m = 0..31 (feature computed on the fly: 1 exp each)
        #pragma unroll 1
        for (int m = 0; m < NCEN; m++) {
            const float diff = d - (float)m * (CUTOFF_R / 31.f);
            const float f = __expf(-4.f * diff * diff);
            #pragma unroll
            for (int o4 = 0; o4 < 16; o4++) {
                const float4 w = w1v[m * 16 + o4];
                a1[4*o4+0] += f * w.x; a1[4*o4+1] += f * w.y;
                a1[4*o4+2] += f * w.z; a1[4*o4+3] += f * w.w;
            }
        }
        // embed rows: m = 32..63 (ei+ej), m = 64..95 (ei*ej)
        const int si8 = species[i] * 8, sj8 = species[j] * 8;
        #pragma unroll 1
        for (int q = 0; q < 8; q++) {
            const float4 a = e4[si8 + q];
            const float4 b = e4[sj8 + q];
            const float fs[4] = {a.x+b.x, a.y+b.y, a.z+b.z, a.w+b.w};
            const float fp[4] = {a.x*b.x, a.y*b.y, a.z*b.z, a.w*b.w};
            #pragma unroll
            for (int c = 0; c < 4; c++) {
                const int ms = 32 + q*4 + c, mp = 64 + q*4 + c;
                #pragma unroll
                for (int o4 = 0; o4 < 16; o4++) {
                    const float4 w = w1v[ms * 16 + o4];
                    a1[4*o4+0] += fs[c] * w.x; a1[4*o4+1] += fs[c] * w.y;
                    a1[4*o4+2] += fs[c] * w.z; a1[4*o4+3] += fs[c] * w.w;
                }
                #pragma unroll
                for (int o4 = 0; o4 < 16; o4++) {
                    const float4 w = w1v[mp * 16 + o4];
                    a1[4*o4+0] += fp[c] * w.x; a1[4*o4+1] += fp[c] * w.y;
                    a1[4*o4+2] += fp[c] * w.z; a1[4*o4+3] += fp[c] * w.w;
                }
            }
        }
        #pragma unroll
        for (int o = 0; o < HID; o++) a1[o] = silu_f(a1[o]);

        // layers 2+3 fused: one scalar a2 live at a time
        float e = b3v;
        #pragma unroll 1
        for (int o = 0; o < HID; o++) {
            float acc = s_b2[o];
            #pragma unroll
            for (int k4 = 0; k4 < 16; k4++) {
                const float4 w = w2v[o * 16 + k4];
                acc += a1[4*k4+0] * w.x + a1[4*k4+1] * w.y
                     + a1[4*k4+2] * w.z + a1[4*k4+3] * w.w;
            }
            e += silu_f(acc) * s_w3[o];
        }
        esum += e * cut;
    }

    s_red[t] = esum;
    __syncthreads();
    for (int s = 128; s > 0; s >>= 1) { if (t < s) s_red[t] += s_red[t + s]; __syncthreads(); }
    if (t == 0 && s_red[0] != 0.f) atomicAdd(e_pair, (double)s_red[0]);
}

// ---------------------------------------------------------------------------
// K5: energy = e_pair + coulomb_scale*e_lr + sum(atom_bias[species])
// ---------------------------------------------------------------------------
__global__ __launch_bounds__(256) void k_final(
    const int* __restrict__ species, const float* __restrict__ atom_bias,
    const float* __restrict__ coulomb_scale,
    const double* __restrict__ e_pair, const double* __restrict__ e_lr,
    float* __restrict__ out_energy)
{
    __shared__ float s_red[256];
    const int t = threadIdx.x;
    float acc = 0.f;
    for (int idx = t; idx < NATOMS; idx += 256) acc += atom_bias[species[idx]];
    s_red[t] = acc;
    __syncthreads();
    for (int s = 128; s > 0; s >>= 1) { if (t < s) s_red[t] += s_red[t + s]; __syncthreads(); }
    if (t == 0) {
        out_energy[0] = (float)(e_pair[0] + (double)coulomb_scale[0] * e_lr[0] + (double)s_red[0]);
    }
}

// ---------------------------------------------------------------------------
extern "C" void kernel_launch(void* const* d_in, const int* in_sizes, int n_in,
                              void* d_out, int out_size, void* d_ws, size_t ws_size,
                              hipStream_t stream) {
    const int*   species       = (const int*)d_in[0];
    const float* pos           = (const float*)d_in[1];
    const float* tq            = (const float*)d_in[2];
    const float* embed         = (const float*)d_in[3];
    const float* W1            = (const float*)d_in[4];
    const float* b1            = (const float*)d_in[5];
    const float* W2            = (const float*)d_in[6];
    const float* b2            = (const float*)d_in[7];
    const float* W3            = (const float*)d_in[8];
    const float* b3            = (const float*)d_in[9];
    const float* atom_bias     = (const float*)d_in[10];
    const float* cW1           = (const float*)d_in[11];
    const float* cb1           = (const float*)d_in[12];
    const float* cW2           = (const float*)d_in[13];
    const float* cb2           = (const float*)d_in[14];
    const float* cW3           = (const float*)d_in[15];
    const float* cb3           = (const float*)d_in[16];
    const float* charge_scale  = (const float*)d_in[17];
    const float* coulomb_scale = (const float*)d_in[18];
    const float* softening     = (const float*)d_in[19];

    char* ws = (char*)d_ws;
    double*   e_pair = (double*)(ws + 0);
    double*   e_lr   = (double*)(ws + 8);
    unsigned* pcount = (unsigned*)(ws + 16);
    float*    raw    = (float*)(ws + 32);
    unsigned* plist  = (unsigned*)(ws + 8192);

    float* out     = (float*)d_out;
    float* charges = out + 1;   // output layout: [energy, charges[1536]]

    hipMemsetAsync(d_ws, 0, 32, stream);  // zero e_pair, e_lr, pcount

    k_local<<<NATOMS, 256, 0, stream>>>(species, pos, tq, embed,
                                        cW1, cb1, cW2, cb2, cW3, cb3,
                                        charge_scale, raw, pcount, plist);
    k_charges<<<1, 256, 0, stream>>>(raw, tq, charges);
    k_lr<<<256, 256, 0, stream>>>(pos, charges, softening, e_lr);
    k_pair<<<768, 256, 0, stream>>>(species, pos, embed,
                                    W1, b1, W2, b2, W3, b3,
                                    pcount, plist, e_pair);
    k_final<<<1, 256, 0, stream>>>(species, atom_bias, coulomb_scale,
                                   e_pair, e_lr, out);
}

// Round 3
// 302.236 us; speedup vs baseline: 2.2529x; 1.7792x over previous
//
#include <hip/hip_runtime.h>
#include <math.h>

#define NATOMS 1536
#define NSPEC 8
#define HID 64
#define NCEN 32
#define CUTOFF_R 5.0f
#define PI_F 3.14159265358979323846f

__device__ __forceinline__ float silu_f(float x) {
    return x / (1.f + __expf(-x));
}

// ---------------------------------------------------------------------------
// K0: transpose W2 into workspace: W2t[o][k] = W2[k][o]  (4096 floats)
// ---------------------------------------------------------------------------
__global__ __launch_bounds__(256) void k_prep(
    const float* __restrict__ W2, float* __restrict__ W2t)
{
    const int idx = blockIdx.x * 256 + threadIdx.x;   // grid = 16 blocks
    const int o = idx >> 6, k = idx & 63;
    W2t[idx] = W2[k * HID + o];
}

// ---------------------------------------------------------------------------
// K1: per-atom block.
//  Phase 1: scan all j; compact in-cutoff neighbors (d,cut,spec) AND the i<j
//           pair j-indices into LDS lists (LDS-counter ballot append — NO
//           per-wave global atomics).
//  Phase 1b: ONE global atomicAdd per block reserves plist space; coalesced
//            copy-out.
//  Phase 2: bank-spread LDS accumulation of species-bucketed RBF basis.
//  Phase 3: charge MLP 289->64->64->1, write raw[i].
// ---------------------------------------------------------------------------
__global__ __launch_bounds__(256) void k_local(
    const int* __restrict__ species, const float* __restrict__ pos,
    const float* __restrict__ tq, const float* __restrict__ embed,
    const float* __restrict__ cW1, const float* __restrict__ cb1,
    const float* __restrict__ cW2, const float* __restrict__ cb2,
    const float* __restrict__ cW3, const float* __restrict__ cb3,
    const float* __restrict__ charge_scale,
    float* __restrict__ raw, unsigned int* __restrict__ pcount,
    unsigned int* __restrict__ plist)
{
    __shared__ float s_local[NSPEC * NCEN];     // [species][center]  1 KB
    __shared__ float d_l[NATOMS];               // 6 KB
    __shared__ float c_l[NATOMS];               // 6 KB
    __shared__ unsigned char sp_l[NATOMS];      // 1.5 KB
    __shared__ unsigned short pj_l[NATOMS];     // 3 KB
    __shared__ unsigned n_cnt, p_cnt, s_base;
    __shared__ float s_pre[64];
    __shared__ float s_h[64];

    const int i = blockIdx.x;
    const int t = threadIdx.x;
    const int lane = t & 63;
    s_local[t] = 0.f;
    if (t == 0) { n_cnt = 0u; p_cnt = 0u; }
    __syncthreads();

    const float xi = pos[3*i+0], yi = pos[3*i+1], zi = pos[3*i+2];
    const int si = species[i];

    // ---- phase 1: neighbor + pair compaction (LDS counters only) ----
    for (int j0 = 0; j0 < NATOMS; j0 += 256) {
        const int j = j0 + t;
        const float dx = xi - pos[3*j+0];
        const float dy = yi - pos[3*j+1];
        const float dz = zi - pos[3*j+2];
        const float d = sqrtf(dx*dx + dy*dy + dz*dz + 1e-12f);
        const bool within = (d < CUTOFF_R) && (j != i);
        const float cut = 0.5f * (__cosf((PI_F / CUTOFF_R) * d) + 1.f);

        const unsigned long long m = __ballot((int)within);
        if (m) {
            const int leader = (int)__ffsll(m) - 1;
            unsigned base = 0;
            if (lane == leader) base = atomicAdd(&n_cnt, (unsigned)__popcll(m));
            base = (unsigned)__shfl((int)base, leader);
            if (within) {
                const unsigned ofs = base + (unsigned)__popcll(m & ((1ull << lane) - 1ull));
                d_l[ofs] = d; c_l[ofs] = cut;
                sp_l[ofs] = (unsigned char)species[j];
            }
        }
        const bool app = (d < CUTOFF_R) && (j > i);
        const unsigned long long m2 = __ballot((int)app);
        if (m2) {
            const int leader = (int)__ffsll(m2) - 1;
            unsigned base = 0;
            if (lane == leader) base = atomicAdd(&p_cnt, (unsigned)__popcll(m2));
            base = (unsigned)__shfl((int)base, leader);
            if (app) {
                const unsigned ofs = base + (unsigned)__popcll(m2 & ((1ull << lane) - 1ull));
                pj_l[ofs] = (unsigned short)j;
            }
        }
    }
    __syncthreads();

    // ---- phase 1b: single global atomic + coalesced copy-out ----
    if (t == 0) s_base = atomicAdd(pcount, p_cnt);
    __syncthreads();
    {
        const unsigned pc = p_cnt, base = s_base;
        for (unsigned idx = (unsigned)t; idx < pc; idx += 256)
            plist[base + idx] = ((unsigned)i << 16) | (unsigned)pj_l[idx];
    }

    // ---- phase 2: dense basis accumulation, bank-spread atomics ----
    {
        const unsigned cnt = n_cnt;
        const int k = t & 31, g = t >> 5;
        const float ck = (float)k * (CUTOFF_R / 31.f);
        for (unsigned n = (unsigned)g; n < cnt; n += 8) {
            const float diff = d_l[n] - ck;
            atomicAdd(&s_local[(int)sp_l[n] * NCEN + k],
                      __expf(-4.f * diff * diff) * c_l[n]);
        }
    }
    __syncthreads();

    // ---- phase 3: charge MLP x = [s_local(256), embed[si](32), Q(1)] ----
    const float Q = tq[0];
    if (t < 64) s_pre[t] = cb1[t];
    __syncthreads();
    {   // layer 1: 289 -> 64; o = lane (coalesced weight loads), k wave-uniform
        const int g = t >> 6, o = t & 63;
        const int k0 = g * 73;
        const int k1 = (g == 3) ? 289 : (k0 + 73);
        float acc = 0.f;
        #pragma unroll 4
        for (int k = k0; k < k1; k++) {
            float xv;
            if (k < 256)      xv = s_local[k];
            else if (k < 288) xv = embed[si * 32 + (k - 256)];
            else              xv = Q;
            acc += xv * cW1[k * 64 + o];
        }
        atomicAdd(&s_pre[o], acc);
    }
    __syncthreads();
    if (t < 64) s_h[t] = silu_f(s_pre[t]);
    __syncthreads();
    if (t < 64) s_pre[t] = cb2[t];
    __syncthreads();
    {   // layer 2: 64 -> 64
        const int g = t >> 6, o = t & 63;
        float acc = 0.f;
        #pragma unroll
        for (int kk = 0; kk < 16; kk++) {
            const int k = g * 16 + kk;
            acc += s_h[k] * cW2[k * 64 + o];
        }
        atomicAdd(&s_pre[o], acc);
    }
    __syncthreads();
    if (t < 64) {   // layer 3: 64 -> 1
        float v = silu_f(s_pre[t]) * cW3[t];
        #pragma unroll
        for (int off = 32; off > 0; off >>= 1) v += __shfl_down(v, off);
        if (t == 0) raw[i] = (v + cb3[0]) * charge_scale[0];
    }
}

// ---------------------------------------------------------------------------
// K2: charges = raw - mean(raw) + Q/N   (single block)
// ---------------------------------------------------------------------------
__global__ __launch_bounds__(256) void k_charges(
    const float* __restrict__ raw, const float* __restrict__ tq,
    float* __restrict__ charges)
{
    __shared__ float s_red[256];
    const int t = threadIdx.x;
    float acc = 0.f;
    for (int idx = t; idx < NATOMS; idx += 256) acc += raw[idx];
    s_red[t] = acc;
    __syncthreads();
    for (int s = 128; s > 0; s >>= 1) { if (t < s) s_red[t] += s_red[t + s]; __syncthreads(); }
    const float mean = s_red[0] / (float)NATOMS;
    const float add = tq[0] / (float)NATOMS;
    for (int idx = t; idx < NATOMS; idx += 256) charges[idx] = raw[idx] - mean + add;
}

// ---------------------------------------------------------------------------
// K3: long-range Coulomb, persistent blocks, per-thread accumulation
// ---------------------------------------------------------------------------
__global__ __launch_bounds__(256) void k_lr(
    const float* __restrict__ pos, const float* __restrict__ charges,
    const float* __restrict__ softening, double* __restrict__ e_lr)
{
    __shared__ float s_red[256];
    const int t = threadIdx.x;
    const float sr = softening[0];
    const float sp = ((sr > 20.f) ? sr : log1pf(__expf(sr))) + 0.001f;
    const float sp2 = sp * sp;
    float acc = 0.f;
    for (int i = blockIdx.x; i < NATOMS; i += gridDim.x) {
        const float xi = pos[3*i+0], yi = pos[3*i+1], zi = pos[3*i+2];
        const float qi = charges[i];
        for (int j = i + 1 + t; j < NATOMS; j += 256) {
            const float dx = xi - pos[3*j+0];
            const float dy = yi - pos[3*j+1];
            const float dz = zi - pos[3*j+2];
            const float d2 = dx*dx + dy*dy + dz*dz + 1e-12f;
            acc += qi * charges[j] * rsqrtf(d2 + sp2);
        }
    }
    s_red[t] = acc;
    __syncthreads();
    for (int s = 128; s > 0; s >>= 1) { if (t < s) s_red[t] += s_red[t + s]; __syncthreads(); }
    if (t == 0 && s_red[0] != 0.f) atomicAdd(e_lr, (double)s_red[0]);
}

// ---------------------------------------------------------------------------
// K4: dense pair MLP over compacted list. Weights read DIRECTLY FROM GLOBAL
// with thread-invariant addresses -> scalar (s_load) path, freeing the LDS
// and VALU pipes entirely for FMAs. W2 pre-transposed in ws so the fused
// layer-2/3 epilogue streams contiguous k. Only h[64] + scalars live.
// ---------------------------------------------------------------------------
__global__ __launch_bounds__(256) void k_pair(
    const int* __restrict__ species, const float* __restrict__ pos,
    const float* __restrict__ embed,
    const float* __restrict__ W1, const float* __restrict__ b1,
    const float* __restrict__ b2,
    const float* __restrict__ W3, const float* __restrict__ b3,
    const float* __restrict__ W2t,
    const unsigned int* __restrict__ pcount, const unsigned int* __restrict__ plist,
    double* __restrict__ e_pair)
{
    __shared__ float s_red[256];
    const int t = threadIdx.x;

    const float4* __restrict__ w1q = (const float4*)W1;   // [m][o4], contiguous o
    const float4* __restrict__ w2q = (const float4*)W2t;  // [o][k4], contiguous k
    const float4* __restrict__ b1q = (const float4*)b1;
    const float4* __restrict__ e4  = (const float4*)embed;
    const float b3v = b3[0];
    const unsigned cnt = *pcount;
    float esum = 0.f;

    for (unsigned p = blockIdx.x * 256u + (unsigned)t; p < cnt; p += gridDim.x * 256u) {
        const unsigned pk = plist[p];
        const int i = (int)(pk >> 16), j = (int)(pk & 0xffffu);
        const float dx = pos[3*i+0] - pos[3*j+0];
        const float dy = pos[3*i+1] - pos[3*j+1];
        const float dz = pos[3*i+2] - pos[3*j+2];
        const float d = sqrtf(dx*dx + dy*dy + dz*dz + 1e-12f);
        const float cut = 0.5f * (__cosf((PI_F / CUTOFF_R) * d) + 1.f);

        float a1[HID];
        #pragma unroll
        for (int o4 = 0; o4 < 16; o4++) {
            const float4 b = b1q[o4];
            a1[4*o4+0] = b.x; a1[4*o4+1] = b.y; a1[4*o4+2] = b.z; a1[4*o4+3] = b.w;
        }

        // RBF rows m = 0..31 (feature on the fly; weights = scalar loads)
        #pragma unroll 2
        for (int m = 0; m < NCEN; m++) {
            const float diff = d - (float)m * (CUTOFF_R / 31.f);
            const float f = __expf(-4.f * diff * diff);
            #pragma unroll
            for (int o4 = 0; o4 < 16; o4++) {
                const float4 w = w1q[m * 16 + o4];
                a1[4*o4+0] += f * w.x; a1[4*o4+1] += f * w.y;
                a1[4*o4+2] += f * w.z; a1[4*o4+3] += f * w.w;
            }
        }
        // embed rows: m = 32..63 (ei+ej), m = 64..95 (ei*ej)
        const int si8 = species[i] * 8, sj8 = species[j] * 8;
        #pragma unroll 1
        for (int q = 0; q < 8; q++) {
            const float4 a = e4[si8 + q];
            const float4 b = e4[sj8 + q];
            const float fs[4] = {a.x+b.x, a.y+b.y, a.z+b.z, a.w+b.w};
            const float fp[4] = {a.x*b.x, a.y*b.y, a.z*b.z, a.w*b.w};
            #pragma unroll
            for (int c = 0; c < 4; c++) {
                const int ms = 32 + q*4 + c, mp = 64 + q*4 + c;
                #pragma unroll
                for (int o4 = 0; o4 < 16; o4++) {
                    const float4 w = w1q[ms * 16 + o4];
                    a1[4*o4+0] += fs[c] * w.x; a1[4*o4+1] += fs[c] * w.y;
                    a1[4*o4+2] += fs[c] * w.z; a1[4*o4+3] += fs[c] * w.w;
                }
                #pragma unroll
                for (int o4 = 0; o4 < 16; o4++) {
                    const float4 w = w1q[mp * 16 + o4];
                    a1[4*o4+0] += fp[c] * w.x; a1[4*o4+1] += fp[c] * w.y;
                    a1[4*o4+2] += fp[c] * w.z; a1[4*o4+3] += fp[c] * w.w;
                }
            }
        }
        #pragma unroll
        for (int o = 0; o < HID; o++) a1[o] = silu_f(a1[o]);

        // layers 2+3 fused: one scalar a2 live at a time, W2t scalar loads
        float e = b3v;
        #pragma unroll 2
        for (int o = 0; o < HID; o++) {
            float acc = b2[o];
            #pragma unroll
            for (int k4 = 0; k4 < 16; k4++) {
                const float4 w = w2q[o * 16 + k4];
                acc += a1[4*k4+0] * w.x + a1[4*k4+1] * w.y
                     + a1[4*k4+2] * w.z + a1[4*k4+3] * w.w;
            }
            e += silu_f(acc) * W3[o];
        }
        esum += e * cut;
    }

    s_red[t] = esum;
    __syncthreads();
    for (int s = 128; s > 0; s >>= 1) { if (t < s) s_red[t] += s_red[t + s]; __syncthreads(); }
    if (t == 0 && s_red[0] != 0.f) atomicAdd(e_pair, (double)s_red[0]);
}

// ---------------------------------------------------------------------------
// K5: energy = e_pair + coulomb_scale*e_lr + sum(atom_bias[species])
// ---------------------------------------------------------------------------
__global__ __launch_bounds__(256) void k_final(
    const int* __restrict__ species, const float* __restrict__ atom_bias,
    const float* __restrict__ coulomb_scale,
    const double* __restrict__ e_pair, const double* __restrict__ e_lr,
    float* __restrict__ out_energy)
{
    __shared__ float s_red[256];
    const int t = threadIdx.x;
    float acc = 0.f;
    for (int idx = t; idx < NATOMS; idx += 256) acc += atom_bias[species[idx]];
    s_red[t] = acc;
    __syncthreads();
    for (int s = 128; s > 0; s >>= 1) { if (t < s) s_red[t] += s_red[t + s]; __syncthreads(); }
    if (t == 0) {
        out_energy[0] = (float)(e_pair[0] + (double)coulomb_scale[0] * e_lr[0] + (double)s_red[0]);
    }
}

// ---------------------------------------------------------------------------
extern "C" void kernel_launch(void* const* d_in, const int* in_sizes, int n_in,
                              void* d_out, int out_size, void* d_ws, size_t ws_size,
                              hipStream_t stream) {
    const int*   species       = (const int*)d_in[0];
    const float* pos           = (const float*)d_in[1];
    const float* tq            = (const float*)d_in[2];
    const float* embed         = (const float*)d_in[3];
    const float* W1            = (const float*)d_in[4];
    const float* b1            = (const float*)d_in[5];
    const float* W2            = (const float*)d_in[6];
    const float* b2            = (const float*)d_in[7];
    const float* W3            = (const float*)d_in[8];
    const float* b3            = (const float*)d_in[9];
    const float* atom_bias     = (const float*)d_in[10];
    const float* cW1           = (const float*)d_in[11];
    const float* cb1           = (const float*)d_in[12];
    const float* cW2           = (const float*)d_in[13];
    const float* cb2           = (const float*)d_in[14];
    const float* cW3           = (const float*)d_in[15];
    const float* cb3           = (const float*)d_in[16];
    const float* charge_scale  = (const float*)d_in[17];
    const float* coulomb_scale = (const float*)d_in[18];
    const float* softening     = (const float*)d_in[19];

    char* ws = (char*)d_ws;
    double*   e_pair = (double*)(ws + 0);
    double*   e_lr   = (double*)(ws + 8);
    unsigned* pcount = (unsigned*)(ws + 16);
    float*    raw    = (float*)(ws + 32);        // 6144 B
    float*    W2t    = (float*)(ws + 8192);      // 16384 B
    unsigned* plist  = (unsigned*)(ws + 32768);  // ~700 KB

    float* out     = (float*)d_out;
    float* charges = out + 1;   // output layout: [energy, charges[1536]]

    hipMemsetAsync(d_ws, 0, 32, stream);  // zero e_pair, e_lr, pcount

    k_prep<<<16, 256, 0, stream>>>(W2, W2t);
    k_local<<<NATOMS, 256, 0, stream>>>(species, pos, tq, embed,
                                        cW1, cb1, cW2, cb2, cW3, cb3,
                                        charge_scale, raw, pcount, plist);
    k_charges<<<1, 256, 0, stream>>>(raw, tq, charges);
    k_lr<<<256, 256, 0, stream>>>(pos, charges, softening, e_lr);
    k_pair<<<768, 256, 0, stream>>>(species, pos, embed,
                                    W1, b1, b2, W3, b3, W2t,
                                    pcount, plist, e_pair);
    k_final<<<1, 256, 0, stream>>>(species, atom_bias, coulomb_scale,
                                   e_pair, e_lr, out);
}

// Round 4
// 252.501 us; speedup vs baseline: 2.6966x; 1.1970x over previous
//
#include <hip/hip_runtime.h>
#include <math.h>

#define NATOMS 1536
#define NSPEC 8
#define HID 64
#define NCEN 32
#define CUTOFF_R 5.0f
#define PI_F 3.14159265358979323846f
#define NBR_CAP 1024   // max in-cutoff neighbors per atom (~560 worst case here)

__device__ __forceinline__ float silu_f(float x) {
    return x / (1.f + __expf(-x));
}

// ---------------------------------------------------------------------------
// K0: transpose W2 into workspace: W2t[o][k] = W2[k][o]  (4096 floats)
// ---------------------------------------------------------------------------
__global__ __launch_bounds__(256) void k_prep(
    const float* __restrict__ W2, float* __restrict__ W2t)
{
    const int idx = blockIdx.x * 256 + threadIdx.x;   // grid = 16 blocks
    const int o = idx >> 6, k = idx & 63;
    W2t[idx] = W2[k * HID + o];
}

// ---------------------------------------------------------------------------
// K1: per-atom block, fully atomic-free on LDS data paths.
//  Phase 1: scan all j (unrolled), ONE ballot-compaction per iter storing
//           (d, cut, species<<11|j). Broadcast via readfirstlane (SALU),
//           not __shfl (no ds_bpermute on the critical path).
//  Phase 1b: derive i<j pair list from neighbor list; one global atomic.
//  Phase 2: per-thread 8-species register buckets (NO LDS atomics),
//           tree-reduced through s_part.
//  Phase 3: charge MLP with LDS partials (NO LDS atomics).
// ---------------------------------------------------------------------------
__global__ __launch_bounds__(256) void k_local(
    const int* __restrict__ species, const float* __restrict__ pos,
    const float* __restrict__ tq, const float* __restrict__ embed,
    const float* __restrict__ cW1, const float* __restrict__ cb1,
    const float* __restrict__ cW2, const float* __restrict__ cb2,
    const float* __restrict__ cW3, const float* __restrict__ cb3,
    const float* __restrict__ charge_scale,
    float* __restrict__ raw, unsigned int* __restrict__ pcount,
    unsigned int* __restrict__ plist)
{
    __shared__ float d_l[NBR_CAP];              // 4 KB
    __shared__ float c_l[NBR_CAP];              // 4 KB
    __shared__ unsigned short spj_l[NBR_CAP];   // 2 KB  (species<<11 | j)
    __shared__ unsigned short pj_l[NBR_CAP];    // 2 KB
    __shared__ float s_part[8 * 256];           // 8 KB  (reused in phase 3)
    __shared__ float s_local[NSPEC * NCEN];     // 1 KB
    __shared__ float s_h[64];
    __shared__ unsigned n_cnt, p_cnt, s_base;

    const int i = blockIdx.x;
    const int t = threadIdx.x;
    const int lane = t & 63;
    if (t == 0) { n_cnt = 0u; p_cnt = 0u; }
    __syncthreads();

    const float xi = pos[3*i+0], yi = pos[3*i+1], zi = pos[3*i+2];
    const int si = species[i];

    // ---- phase 1: neighbor compaction (single ballot per iter) ----
    #pragma unroll
    for (int j0 = 0; j0 < NATOMS; j0 += 256) {
        const int j = j0 + t;
        const float dx = xi - pos[3*j+0];
        const float dy = yi - pos[3*j+1];
        const float dz = zi - pos[3*j+2];
        const float d = sqrtf(dx*dx + dy*dy + dz*dz + 1e-12f);
        const bool within = (d < CUTOFF_R) && (j != i);
        const unsigned long long m = __ballot((int)within);
        if (within) {
            const unsigned prefix = (unsigned)__popcll(m & ((1ull << lane) - 1ull));
            unsigned base = 0;
            if (prefix == 0) base = atomicAdd(&n_cnt, (unsigned)__popcll(m));
            base = (unsigned)__builtin_amdgcn_readfirstlane((int)base);
            const unsigned ofs = base + prefix;
            if (ofs < NBR_CAP) {
                d_l[ofs] = d;
                c_l[ofs] = 0.5f * (__cosf((PI_F / CUTOFF_R) * d) + 1.f);
                spj_l[ofs] = (unsigned short)((species[j] << 11) | j);
            }
        }
    }
    __syncthreads();
    const unsigned cnt = (n_cnt < NBR_CAP) ? n_cnt : NBR_CAP;

    // ---- phase 1b: pair list (j > i) from neighbor list ----
    for (unsigned n0 = 0; n0 < cnt; n0 += 256) {
        const unsigned n = n0 + (unsigned)t;
        bool app = false; int jj = 0;
        if (n < cnt) { jj = (int)(spj_l[n] & 2047u); app = (jj > i); }
        const unsigned long long m = __ballot((int)app);
        if (app) {
            const unsigned prefix = (unsigned)__popcll(m & ((1ull << lane) - 1ull));
            unsigned base = 0;
            if (prefix == 0) base = atomicAdd(&p_cnt, (unsigned)__popcll(m));
            base = (unsigned)__builtin_amdgcn_readfirstlane((int)base);
            pj_l[base + prefix] = (unsigned short)jj;
        }
    }
    __syncthreads();
    if (t == 0) s_base = atomicAdd(pcount, p_cnt);
    __syncthreads();
    {
        const unsigned pc = p_cnt, base = s_base;
        for (unsigned idx = (unsigned)t; idx < pc; idx += 256)
            plist[base + idx] = ((unsigned)i << 16) | (unsigned)pj_l[idx];
    }

    // ---- phase 2: register-bucket basis accumulation (atomic-free) ----
    {
        const int k = t & 31, g = t >> 5;
        const float ck = (float)k * (CUTOFF_R / 31.f);
        float f0=0.f,f1=0.f,f2=0.f,f3=0.f,f4=0.f,f5=0.f,f6=0.f,f7=0.f;
        for (unsigned n = (unsigned)g; n < cnt; n += 8) {
            const float diff = d_l[n] - ck;
            const float v = __expf(-4.f * diff * diff) * c_l[n];
            const int sp = (int)(spj_l[n] >> 11);
            f0 += (sp == 0) ? v : 0.f;
            f1 += (sp == 1) ? v : 0.f;
            f2 += (sp == 2) ? v : 0.f;
            f3 += (sp == 3) ? v : 0.f;
            f4 += (sp == 4) ? v : 0.f;
            f5 += (sp == 5) ? v : 0.f;
            f6 += (sp == 6) ? v : 0.f;
            f7 += (sp == 7) ? v : 0.f;
        }
        float* sp_g = &s_part[g * 256 + k];
        sp_g[0*32] = f0; sp_g[1*32] = f1; sp_g[2*32] = f2; sp_g[3*32] = f3;
        sp_g[4*32] = f4; sp_g[5*32] = f5; sp_g[6*32] = f6; sp_g[7*32] = f7;
    }
    __syncthreads();
    {
        float acc = 0.f;
        #pragma unroll
        for (int g2 = 0; g2 < 8; g2++) acc += s_part[g2 * 256 + t];
        s_local[t] = acc;
    }
    __syncthreads();

    // ---- phase 3: charge MLP x = [s_local(256), embed[si](32), Q(1)] ----
    const float Q = tq[0];
    {   // layer 1: 289 -> 64, partials in s_part (no atomics)
        const int g3 = t >> 6, o = t & 63;
        const int k0 = g3 * 73;
        const int k1 = (g3 == 3) ? 289 : (k0 + 73);
        float acc = 0.f;
        #pragma unroll 4
        for (int k = k0; k < k1; k++) {
            float xv;
            if (k < 256)      xv = s_local[k];
            else if (k < 288) xv = embed[si * 32 + (k - 256)];
            else              xv = Q;
            acc += xv * cW1[k * 64 + o];
        }
        s_part[g3 * 64 + o] = acc;
    }
    __syncthreads();
    if (t < 64) {
        const float a = cb1[t] + s_part[t] + s_part[64 + t]
                      + s_part[128 + t] + s_part[192 + t];
        s_h[t] = silu_f(a);
    }
    __syncthreads();
    {   // layer 2: 64 -> 64, partials
        const int g3 = t >> 6, o = t & 63;
        float acc = 0.f;
        #pragma unroll
        for (int kk = 0; kk < 16; kk++) {
            const int k = g3 * 16 + kk;
            acc += s_h[k] * cW2[k * 64 + o];
        }
        s_part[g3 * 64 + o] = acc;
    }
    __syncthreads();
    if (t < 64) {   // layer 3: 64 -> 1
        const float a = cb2[t] + s_part[t] + s_part[64 + t]
                      + s_part[128 + t] + s_part[192 + t];
        float v = silu_f(a) * cW3[t];
        #pragma unroll
        for (int off = 32; off > 0; off >>= 1) v += __shfl_down(v, off);
        if (t == 0) raw[i] = (v + cb3[0]) * charge_scale[0];
    }
}

// ---------------------------------------------------------------------------
// K2: charges = raw - mean(raw) + Q/N   (single block)
// ---------------------------------------------------------------------------
__global__ __launch_bounds__(256) void k_charges(
    const float* __restrict__ raw, const float* __restrict__ tq,
    float* __restrict__ charges)
{
    __shared__ float s_red[256];
    const int t = threadIdx.x;
    float acc = 0.f;
    for (int idx = t; idx < NATOMS; idx += 256) acc += raw[idx];
    s_red[t] = acc;
    __syncthreads();
    for (int s = 128; s > 0; s >>= 1) { if (t < s) s_red[t] += s_red[t + s]; __syncthreads(); }
    const float mean = s_red[0] / (float)NATOMS;
    const float add = tq[0] / (float)NATOMS;
    for (int idx = t; idx < NATOMS; idx += 256) charges[idx] = raw[idx] - mean + add;
}

// ---------------------------------------------------------------------------
// K3: long-range Coulomb, persistent blocks, per-thread accumulation
// ---------------------------------------------------------------------------
__global__ __launch_bounds__(256) void k_lr(
    const float* __restrict__ pos, const float* __restrict__ charges,
    const float* __restrict__ softening, double* __restrict__ e_lr)
{
    __shared__ float s_red[256];
    const int t = threadIdx.x;
    const float sr = softening[0];
    const float sp = ((sr > 20.f) ? sr : log1pf(__expf(sr))) + 0.001f;
    const float sp2 = sp * sp;
    float acc = 0.f;
    for (int i = blockIdx.x; i < NATOMS; i += gridDim.x) {
        const float xi = pos[3*i+0], yi = pos[3*i+1], zi = pos[3*i+2];
        const float qi = charges[i];
        for (int j = i + 1 + t; j < NATOMS; j += 256) {
            const float dx = xi - pos[3*j+0];
            const float dy = yi - pos[3*j+1];
            const float dz = zi - pos[3*j+2];
            const float d2 = dx*dx + dy*dy + dz*dz + 1e-12f;
            acc += qi * charges[j] * rsqrtf(d2 + sp2);
        }
    }
    s_red[t] = acc;
    __syncthreads();
    for (int s = 128; s > 0; s >>= 1) { if (t < s) s_red[t] += s_red[t + s]; __syncthreads(); }
    if (t == 0 && s_red[0] != 0.f) atomicAdd(e_lr, (double)s_red[0]);
}

// ---------------------------------------------------------------------------
// K4: dense pair MLP, P=2 register tiling: each thread carries TWO pairs so
// the uniform (scalar-path) weight stream is amortized over 2x the FMAs.
// Weights from global with thread-invariant addresses; W2 pre-transposed.
// ---------------------------------------------------------------------------
__global__ __launch_bounds__(256) void k_pair(
    const int* __restrict__ species, const float* __restrict__ pos,
    const float* __restrict__ embed,
    const float* __restrict__ W1, const float* __restrict__ b1,
    const float* __restrict__ b2,
    const float* __restrict__ W3, const float* __restrict__ b3,
    const float* __restrict__ W2t,
    const unsigned int* __restrict__ pcount, const unsigned int* __restrict__ plist,
    double* __restrict__ e_pair)
{
    __shared__ float s_red[256];
    const int t = threadIdx.x;

    const float4* __restrict__ w1q = (const float4*)W1;   // [m][o4]
    const float4* __restrict__ w2q = (const float4*)W2t;  // [o][k4]
    const float4* __restrict__ b1q = (const float4*)b1;
    const float4* __restrict__ e4  = (const float4*)embed;
    const float b3v = b3[0];
    const unsigned cnt = *pcount;
    float esum = 0.f;

    for (unsigned base = blockIdx.x * 512u; base < cnt; base += gridDim.x * 512u) {
        const unsigned pA = base + (unsigned)t;
        const unsigned pB = pA + 256u;
        const bool vA = pA < cnt, vB = pB < cnt;
        int iA = 0, jA = 0, iB = 0, jB = 0;
        if (vA) { const unsigned pk = plist[pA]; iA = (int)(pk >> 16); jA = (int)(pk & 0xffffu); }
        if (vB) { const unsigned pk = plist[pB]; iB = (int)(pk >> 16); jB = (int)(pk & 0xffffu); }
        float dA, dB, cutA, cutB;
        {
            const float dx = pos[3*iA+0] - pos[3*jA+0];
            const float dy = pos[3*iA+1] - pos[3*jA+1];
            const float dz = pos[3*iA+2] - pos[3*jA+2];
            dA = sqrtf(dx*dx + dy*dy + dz*dz + 1e-12f);
            cutA = vA ? 0.5f * (__cosf((PI_F / CUTOFF_R) * dA) + 1.f) : 0.f;
        }
        {
            const float dx = pos[3*iB+0] - pos[3*jB+0];
            const float dy = pos[3*iB+1] - pos[3*jB+1];
            const float dz = pos[3*iB+2] - pos[3*jB+2];
            dB = sqrtf(dx*dx + dy*dy + dz*dz + 1e-12f);
            cutB = vB ? 0.5f * (__cosf((PI_F / CUTOFF_R) * dB) + 1.f) : 0.f;
        }

        float aA[HID], aB[HID];
        #pragma unroll
        for (int o4 = 0; o4 < 16; o4++) {
            const float4 b = b1q[o4];
            aA[4*o4+0] = b.x; aA[4*o4+1] = b.y; aA[4*o4+2] = b.z; aA[4*o4+3] = b.w;
            aB[4*o4+0] = b.x; aB[4*o4+1] = b.y; aB[4*o4+2] = b.z; aB[4*o4+3] = b.w;
        }

        // RBF rows m = 0..31 — one weight vector feeds both pairs
        #pragma unroll 2
        for (int m = 0; m < NCEN; m++) {
            const float cm = (float)m * (CUTOFF_R / 31.f);
            const float dfA = dA - cm, dfB = dB - cm;
            const float fA = __expf(-4.f * dfA * dfA);
            const float fB = __expf(-4.f * dfB * dfB);
            #pragma unroll
            for (int o4 = 0; o4 < 16; o4++) {
                const float4 w = w1q[m * 16 + o4];
                aA[4*o4+0] += fA * w.x; aA[4*o4+1] += fA * w.y;
                aA[4*o4+2] += fA * w.z; aA[4*o4+3] += fA * w.w;
                aB[4*o4+0] += fB * w.x; aB[4*o4+1] += fB * w.y;
                aB[4*o4+2] += fB * w.z; aB[4*o4+3] += fB * w.w;
            }
        }
        // embed rows: m = 32..63 (ei+ej), m = 64..95 (ei*ej)
        const int siA8 = species[iA] * 8, sjA8 = species[jA] * 8;
        const int siB8 = species[iB] * 8, sjB8 = species[jB] * 8;
        #pragma unroll 1
        for (int q = 0; q < 8; q++) {
            const float4 a1v = e4[siA8 + q], b1v = e4[sjA8 + q];
            const float4 a2v = e4[siB8 + q], b2v = e4[sjB8 + q];
            const float fsA[4] = {a1v.x+b1v.x, a1v.y+b1v.y, a1v.z+b1v.z, a1v.w+b1v.w};
            const float fpA[4] = {a1v.x*b1v.x, a1v.y*b1v.y, a1v.z*b1v.z, a1v.w*b1v.w};
            const float fsB[4] = {a2v.x+b2v.x, a2v.y+b2v.y, a2v.z+b2v.z, a2v.w+b2v.w};
            const float fpB[4] = {a2v.x*b2v.x, a2v.y*b2v.y, a2v.z*b2v.z, a2v.w*b2v.w};
            #pragma unroll
            for (int c = 0; c < 4; c++) {
                const int ms = 32 + q*4 + c, mp = 64 + q*4 + c;
                #pragma unroll
                for (int o4 = 0; o4 < 16; o4++) {
                    const float4 w = w1q[ms * 16 + o4];
                    aA[4*o4+0] += fsA[c] * w.x; aA[4*o4+1] += fsA[c] * w.y;
                    aA[4*o4+2] += fsA[c] * w.z; aA[4*o4+3] += fsA[c] * w.w;
                    aB[4*o4+0] += fsB[c] * w.x; aB[4*o4+1] += fsB[c] * w.y;
                    aB[4*o4+2] += fsB[c] * w.z; aB[4*o4+3] += fsB[c] * w.w;
                }
                #pragma unroll
                for (int o4 = 0; o4 < 16; o4++) {
                    const float4 w = w1q[mp * 16 + o4];
                    aA[4*o4+0] += fpA[c] * w.x; aA[4*o4+1] += fpA[c] * w.y;
                    aA[4*o4+2] += fpA[c] * w.z; aA[4*o4+3] += fpA[c] * w.w;
                    aB[4*o4+0] += fpB[c] * w.x; aB[4*o4+1] += fpB[c] * w.y;
                    aB[4*o4+2] += fpB[c] * w.z; aB[4*o4+3] += fpB[c] * w.w;
                }
            }
        }
        #pragma unroll
        for (int o = 0; o < HID; o++) { aA[o] = silu_f(aA[o]); aB[o] = silu_f(aB[o]); }

        // layers 2+3 fused, shared W2t stream
        float eA = b3v, eB = b3v;
        #pragma unroll 2
        for (int o = 0; o < HID; o++) {
            float accA = b2[o], accB = accA;
            #pragma unroll
            for (int k4 = 0; k4 < 16; k4++) {
                const float4 w = w2q[o * 16 + k4];
                accA += aA[4*k4+0]*w.x + aA[4*k4+1]*w.y + aA[4*k4+2]*w.z + aA[4*k4+3]*w.w;
                accB += aB[4*k4+0]*w.x + aB[4*k4+1]*w.y + aB[4*k4+2]*w.z + aB[4*k4+3]*w.w;
            }
            const float w3o = W3[o];
            eA += silu_f(accA) * w3o;
            eB += silu_f(accB) * w3o;
        }
        esum += eA * cutA + eB * cutB;
    }

    s_red[t] = esum;
    __syncthreads();
    for (int s = 128; s > 0; s >>= 1) { if (t < s) s_red[t] += s_red[t + s]; __syncthreads(); }
    if (t == 0 && s_red[0] != 0.f) atomicAdd(e_pair, (double)s_red[0]);
}

// ---------------------------------------------------------------------------
// K5: energy = e_pair + coulomb_scale*e_lr + sum(atom_bias[species])
// ---------------------------------------------------------------------------
__global__ __launch_bounds__(256) void k_final(
    const int* __restrict__ species, const float* __restrict__ atom_bias,
    const float* __restrict__ coulomb_scale,
    const double* __restrict__ e_pair, const double* __restrict__ e_lr,
    float* __restrict__ out_energy)
{
    __shared__ float s_red[256];
    const int t = threadIdx.x;
    float acc = 0.f;
    for (int idx = t; idx < NATOMS; idx += 256) acc += atom_bias[species[idx]];
    s_red[t] = acc;
    __syncthreads();
    for (int s = 128; s > 0; s >>= 1) { if (t < s) s_red[t] += s_red[t + s]; __syncthreads(); }
    if (t == 0) {
        out_energy[0] = (float)(e_pair[0] + (double)coulomb_scale[0] * e_lr[0] + (double)s_red[0]);
    }
}

// ---------------------------------------------------------------------------
extern "C" void kernel_launch(void* const* d_in, const int* in_sizes, int n_in,
                              void* d_out, int out_size, void* d_ws, size_t ws_size,
                              hipStream_t stream) {
    const int*   species       = (const int*)d_in[0];
    const float* pos           = (const float*)d_in[1];
    const float* tq            = (const float*)d_in[2];
    const float* embed         = (const float*)d_in[3];
    const float* W1            = (const float*)d_in[4];
    const float* b1            = (const float*)d_in[5];
    const float* W2            = (const float*)d_in[6];
    const float* b2            = (const float*)d_in[7];
    const float* W3            = (const float*)d_in[8];
    const float* b3            = (const float*)d_in[9];
    const float* atom_bias     = (const float*)d_in[10];
    const float* cW1           = (const float*)d_in[11];
    const float* cb1           = (const float*)d_in[12];
    const float* cW2           = (const float*)d_in[13];
    const float* cb2           = (const float*)d_in[14];
    const float* cW3           = (const float*)d_in[15];
    const float* cb3           = (const float*)d_in[16];
    const float* charge_scale  = (const float*)d_in[17];
    const float* coulomb_scale = (const float*)d_in[18];
    const float* softening     = (const float*)d_in[19];

    char* ws = (char*)d_ws;
    double*   e_pair = (double*)(ws + 0);
    double*   e_lr   = (double*)(ws + 8);
    unsigned* pcount = (unsigned*)(ws + 16);
    float*    raw    = (float*)(ws + 32);        // 6144 B
    float*    W2t    = (float*)(ws + 8192);      // 16384 B
    unsigned* plist  = (unsigned*)(ws + 32768);  // ~700 KB

    float* out     = (float*)d_out;
    float* charges = out + 1;   // output layout: [energy, charges[1536]]

    hipMemsetAsync(d_ws, 0, 32, stream);  // zero e_pair, e_lr, pcount

    k_prep<<<16, 256, 0, stream>>>(W2, W2t);
    k_local<<<NATOMS, 256, 0, stream>>>(species, pos, tq, embed,
                                        cW1, cb1, cW2, cb2, cW3, cb3,
                                        charge_scale, raw, pcount, plist);
    k_charges<<<1, 256, 0, stream>>>(raw, tq, charges);
    k_lr<<<512, 256, 0, stream>>>(pos, charges, softening, e_lr);
    k_pair<<<512, 256, 0, stream>>>(species, pos, embed,
                                    W1, b1, b2, W3, b3, W2t,
                                    pcount, plist, e_pair);
    k_final<<<1, 256, 0, stream>>>(species, atom_bias, coulomb_scale,
                                   e_pair, e_lr, out);
}

// Round 5
// 211.247 us; speedup vs baseline: 3.2232x; 1.1953x over previous
//
#include <hip/hip_runtime.h>
#include <math.h>

#define NATOMS 1536
#define NSPEC 8
#define HID 64
#define NCEN 32
#define CUTOFF_R 5.0f
#define PI_F 3.14159265358979323846f
#define NBR_CAP 1024   // max in-cutoff neighbors per atom (~560 worst case here)

__device__ __forceinline__ float silu_f(float x) {
    return x / (1.f + __expf(-x));
}

// ---------------------------------------------------------------------------
// K0: prep.
//  blocks 0..15 : W2t[o][k] = W2[k][o]                  (4096 floats)
//  blocks 16..79: ctab[c][o] = b1[o] + sum_k (ei+ej)[k]*W1[32+k][o]
//                                + (ei*ej)[k]*W1[64+k][o]   for c=si*8+sj
// ---------------------------------------------------------------------------
__global__ __launch_bounds__(256) void k_prep(
    const float* __restrict__ W1, const float* __restrict__ b1,
    const float* __restrict__ W2, const float* __restrict__ embed,
    float* __restrict__ W2t, float* __restrict__ ctab)
{
    const int b = blockIdx.x;
    const int t = threadIdx.x;
    if (b < 16) {
        const int idx = b * 256 + t;
        const int o = idx >> 6, k = idx & 63;
        W2t[idx] = W2[k * HID + o];
    } else if (t < 64) {
        const int c = b - 16;             // combo
        const int si = c >> 3, sj = c & 7;
        const int o = t;
        float acc = b1[o];
        #pragma unroll 4
        for (int k = 0; k < 32; k++) {
            const float a = embed[si * 32 + k];
            const float bb = embed[sj * 32 + k];
            acc += (a + bb) * W1[(32 + k) * HID + o];
            acc += (a * bb) * W1[(64 + k) * HID + o];
        }
        ctab[c * HID + o] = acc;
    }
}

// ---------------------------------------------------------------------------
// K1: per-atom block, atomic-free LDS data paths.
//  Phase 1: neighbor compaction (one ballot per iter; readfirstlane bcast).
//  Phase 1b: pair list (j>i) packed as (combo<<22 | i<<11 | j); one global
//            atomic per block.
//  Phase 2: per-thread 8-species register buckets, tree-reduced in LDS.
//  Phase 3: charge MLP 289->64->64->1 with LDS partials.
// ---------------------------------------------------------------------------
__global__ __launch_bounds__(256) void k_local(
    const int* __restrict__ species, const float* __restrict__ pos,
    const float* __restrict__ tq, const float* __restrict__ embed,
    const float* __restrict__ cW1, const float* __restrict__ cb1,
    const float* __restrict__ cW2, const float* __restrict__ cb2,
    const float* __restrict__ cW3, const float* __restrict__ cb3,
    const float* __restrict__ charge_scale,
    float* __restrict__ raw, unsigned int* __restrict__ pcount,
    unsigned int* __restrict__ plist)
{
    __shared__ float d_l[NBR_CAP];              // 4 KB
    __shared__ float c_l[NBR_CAP];              // 4 KB
    __shared__ unsigned short spj_l[NBR_CAP];   // 2 KB  (species<<11 | j)
    __shared__ unsigned short pj_l[NBR_CAP];    // 2 KB  (species<<11 | j), j>i
    __shared__ float s_part[8 * 256];           // 8 KB  (reused in phase 3)
    __shared__ float s_local[NSPEC * NCEN];     // 1 KB
    __shared__ float s_h[64];
    __shared__ unsigned n_cnt, p_cnt, s_base;

    const int i = blockIdx.x;
    const int t = threadIdx.x;
    const int lane = t & 63;
    if (t == 0) { n_cnt = 0u; p_cnt = 0u; }
    __syncthreads();

    const float xi = pos[3*i+0], yi = pos[3*i+1], zi = pos[3*i+2];
    const int si = species[i];

    // ---- phase 1: neighbor compaction ----
    #pragma unroll
    for (int j0 = 0; j0 < NATOMS; j0 += 256) {
        const int j = j0 + t;
        const float dx = xi - pos[3*j+0];
        const float dy = yi - pos[3*j+1];
        const float dz = zi - pos[3*j+2];
        const float d = sqrtf(dx*dx + dy*dy + dz*dz + 1e-12f);
        const bool within = (d < CUTOFF_R) && (j != i);
        const unsigned long long m = __ballot((int)within);
        if (within) {
            const unsigned prefix = (unsigned)__popcll(m & ((1ull << lane) - 1ull));
            unsigned base = 0;
            if (prefix == 0) base = atomicAdd(&n_cnt, (unsigned)__popcll(m));
            base = (unsigned)__builtin_amdgcn_readfirstlane((int)base);
            const unsigned ofs = base + prefix;
            if (ofs < NBR_CAP) {
                d_l[ofs] = d;
                c_l[ofs] = 0.5f * (__cosf((PI_F / CUTOFF_R) * d) + 1.f);
                spj_l[ofs] = (unsigned short)((species[j] << 11) | j);
            }
        }
    }
    __syncthreads();
    const unsigned cnt = (n_cnt < NBR_CAP) ? n_cnt : NBR_CAP;

    // ---- phase 1b: pair list (j > i) ----
    for (unsigned n0 = 0; n0 < cnt; n0 += 256) {
        const unsigned n = n0 + (unsigned)t;
        bool app = false; unsigned short w = 0;
        if (n < cnt) { w = spj_l[n]; app = ((int)(w & 2047u) > i); }
        const unsigned long long m = __ballot((int)app);
        if (app) {
            const unsigned prefix = (unsigned)__popcll(m & ((1ull << lane) - 1ull));
            unsigned base = 0;
            if (prefix == 0) base = atomicAdd(&p_cnt, (unsigned)__popcll(m));
            base = (unsigned)__builtin_amdgcn_readfirstlane((int)base);
            pj_l[base + prefix] = w;
        }
    }
    __syncthreads();
    if (t == 0) s_base = atomicAdd(pcount, p_cnt);
    __syncthreads();
    {
        const unsigned pc = p_cnt, base = s_base;
        for (unsigned idx = (unsigned)t; idx < pc; idx += 256) {
            const unsigned w = pj_l[idx];
            const unsigned jj = w & 2047u, spj = w >> 11;
            // packed: combo(6) | i(11) | j(11)
            plist[base + idx] = (((unsigned)si * 8u + spj) << 22)
                              | ((unsigned)i << 11) | jj;
        }
    }

    // ---- phase 2: register-bucket basis accumulation ----
    {
        const int k = t & 31, g = t >> 5;
        const float ck = (float)k * (CUTOFF_R / 31.f);
        float f0=0.f,f1=0.f,f2=0.f,f3=0.f,f4=0.f,f5=0.f,f6=0.f,f7=0.f;
        for (unsigned n = (unsigned)g; n < cnt; n += 8) {
            const float diff = d_l[n] - ck;
            const float v = __expf(-4.f * diff * diff) * c_l[n];
            const int sp = (int)(spj_l[n] >> 11);
            f0 += (sp == 0) ? v : 0.f;
            f1 += (sp == 1) ? v : 0.f;
            f2 += (sp == 2) ? v : 0.f;
            f3 += (sp == 3) ? v : 0.f;
            f4 += (sp == 4) ? v : 0.f;
            f5 += (sp == 5) ? v : 0.f;
            f6 += (sp == 6) ? v : 0.f;
            f7 += (sp == 7) ? v : 0.f;
        }
        float* sp_g = &s_part[g * 256 + k];
        sp_g[0*32] = f0; sp_g[1*32] = f1; sp_g[2*32] = f2; sp_g[3*32] = f3;
        sp_g[4*32] = f4; sp_g[5*32] = f5; sp_g[6*32] = f6; sp_g[7*32] = f7;
    }
    __syncthreads();
    {
        float acc = 0.f;
        #pragma unroll
        for (int g2 = 0; g2 < 8; g2++) acc += s_part[g2 * 256 + t];
        s_local[t] = acc;
    }
    __syncthreads();

    // ---- phase 3: charge MLP x = [s_local(256), embed[si](32), Q(1)] ----
    const float Q = tq[0];
    {   // layer 1: 289 -> 64, partials
        const int g3 = t >> 6, o = t & 63;
        const int k0 = g3 * 73;
        const int k1 = (g3 == 3) ? 289 : (k0 + 73);
        float acc = 0.f;
        #pragma unroll 4
        for (int k = k0; k < k1; k++) {
            float xv;
            if (k < 256)      xv = s_local[k];
            else if (k < 288) xv = embed[si * 32 + (k - 256)];
            else              xv = Q;
            acc += xv * cW1[k * 64 + o];
        }
        s_part[g3 * 64 + o] = acc;
    }
    __syncthreads();
    if (t < 64) {
        const float a = cb1[t] + s_part[t] + s_part[64 + t]
                      + s_part[128 + t] + s_part[192 + t];
        s_h[t] = silu_f(a);
    }
    __syncthreads();
    {   // layer 2: 64 -> 64, partials
        const int g3 = t >> 6, o = t & 63;
        float acc = 0.f;
        #pragma unroll
        for (int kk = 0; kk < 16; kk++) {
            const int k = g3 * 16 + kk;
            acc += s_h[k] * cW2[k * 64 + o];
        }
        s_part[g3 * 64 + o] = acc;
    }
    __syncthreads();
    if (t < 64) {   // layer 3: 64 -> 1
        const float a = cb2[t] + s_part[t] + s_part[64 + t]
                      + s_part[128 + t] + s_part[192 + t];
        float v = silu_f(a) * cW3[t];
        #pragma unroll
        for (int off = 32; off > 0; off >>= 1) v += __shfl_down(v, off);
        if (t == 0) raw[i] = (v + cb3[0]) * charge_scale[0];
    }
}

// ---------------------------------------------------------------------------
// K2: charges = raw - mean(raw) + Q/N   (single block)
// ---------------------------------------------------------------------------
__global__ __launch_bounds__(256) void k_charges(
    const float* __restrict__ raw, const float* __restrict__ tq,
    float* __restrict__ charges)
{
    __shared__ float s_red[256];
    const int t = threadIdx.x;
    float acc = 0.f;
    for (int idx = t; idx < NATOMS; idx += 256) acc += raw[idx];
    s_red[t] = acc;
    __syncthreads();
    for (int s = 128; s > 0; s >>= 1) { if (t < s) s_red[t] += s_red[t + s]; __syncthreads(); }
    const float mean = s_red[0] / (float)NATOMS;
    const float add = tq[0] / (float)NATOMS;
    for (int idx = t; idx < NATOMS; idx += 256) charges[idx] = raw[idx] - mean + add;
}

// ---------------------------------------------------------------------------
// K3: long-range Coulomb, persistent blocks
// ---------------------------------------------------------------------------
__global__ __launch_bounds__(256) void k_lr(
    const float* __restrict__ pos, const float* __restrict__ charges,
    const float* __restrict__ softening, double* __restrict__ e_lr)
{
    __shared__ float s_red[256];
    const int t = threadIdx.x;
    const float sr = softening[0];
    const float sp = ((sr > 20.f) ? sr : log1pf(__expf(sr))) + 0.001f;
    const float sp2 = sp * sp;
    float acc = 0.f;
    for (int i = blockIdx.x; i < NATOMS; i += gridDim.x) {
        const float xi = pos[3*i+0], yi = pos[3*i+1], zi = pos[3*i+2];
        const float qi = charges[i];
        for (int j = i + 1 + t; j < NATOMS; j += 256) {
            const float dx = xi - pos[3*j+0];
            const float dy = yi - pos[3*j+1];
            const float dz = zi - pos[3*j+2];
            const float d2 = dx*dx + dy*dy + dz*dz + 1e-12f;
            acc += qi * charges[j] * rsqrtf(d2 + sp2);
        }
    }
    s_red[t] = acc;
    __syncthreads();
    for (int s = 128; s > 0; s >>= 1) { if (t < s) s_red[t] += s_red[t + s]; __syncthreads(); }
    if (t == 0 && s_red[0] != 0.f) atomicAdd(e_lr, (double)s_red[0]);
}

// ---------------------------------------------------------------------------
// K4: dense pair MLP. P=1, spill-free (~64 acc regs). Layer-1 embed part
// folded into ctab[combo] (computed in k_prep) -> only 32 RBF K-rows remain.
// Weights streamed from global with wave-uniform addresses (scalar path);
// W2 pre-transposed. Layers 2+3 fused (one scalar live).
// ---------------------------------------------------------------------------
__global__ __launch_bounds__(256) void k_pair(
    const float* __restrict__ pos,
    const float* __restrict__ W1,
    const float* __restrict__ b2,
    const float* __restrict__ W3, const float* __restrict__ b3,
    const float* __restrict__ W2t, const float* __restrict__ ctab,
    const unsigned int* __restrict__ pcount, const unsigned int* __restrict__ plist,
    double* __restrict__ e_pair)
{
    __shared__ float s_red[256];
    const int t = threadIdx.x;

    const float4* __restrict__ w1q = (const float4*)W1;   // rows m=0..31, [m][o4]
    const float4* __restrict__ w2q = (const float4*)W2t;  // [o][k4]
    const float4* __restrict__ ct4 = (const float4*)ctab; // [combo][o4]
    const float b3v = b3[0];
    const unsigned cnt = *pcount;
    float esum = 0.f;

    for (unsigned p = blockIdx.x * 256u + (unsigned)t; p < cnt; p += gridDim.x * 256u) {
        const unsigned pk = plist[p];
        const int combo = (int)(pk >> 22);
        const int i = (int)((pk >> 11) & 2047u);
        const int j = (int)(pk & 2047u);
        const float dx = pos[3*i+0] - pos[3*j+0];
        const float dy = pos[3*i+1] - pos[3*j+1];
        const float dz = pos[3*i+2] - pos[3*j+2];
        const float d = sqrtf(dx*dx + dy*dy + dz*dz + 1e-12f);
        const float cut = 0.5f * (__cosf((PI_F / CUTOFF_R) * d) + 1.f);

        // a1 init = combo table row (per-lane vector loads, L1-resident)
        float a1[HID];
        #pragma unroll
        for (int o4 = 0; o4 < 16; o4++) {
            const float4 c = ct4[combo * 16 + o4];
            a1[4*o4+0] = c.x; a1[4*o4+1] = c.y; a1[4*o4+2] = c.z; a1[4*o4+3] = c.w;
        }

        // RBF rows m = 0..31 (weights on scalar path)
        #pragma unroll 2
        for (int m = 0; m < NCEN; m++) {
            const float diff = d - (float)m * (CUTOFF_R / 31.f);
            const float f = __expf(-4.f * diff * diff);
            #pragma unroll
            for (int o4 = 0; o4 < 16; o4++) {
                const float4 w = w1q[m * 16 + o4];
                a1[4*o4+0] += f * w.x; a1[4*o4+1] += f * w.y;
                a1[4*o4+2] += f * w.z; a1[4*o4+3] += f * w.w;
            }
        }
        #pragma unroll
        for (int o = 0; o < HID; o++) a1[o] = silu_f(a1[o]);

        // layers 2+3 fused
        float e = b3v;
        #pragma unroll 2
        for (int o = 0; o < HID; o++) {
            float acc = b2[o];
            #pragma unroll
            for (int k4 = 0; k4 < 16; k4++) {
                const float4 w = w2q[o * 16 + k4];
                acc += a1[4*k4+0]*w.x + a1[4*k4+1]*w.y
                     + a1[4*k4+2]*w.z + a1[4*k4+3]*w.w;
            }
            e += silu_f(acc) * W3[o];
        }
        esum += e * cut;
    }

    s_red[t] = esum;
    __syncthreads();
    for (int s = 128; s > 0; s >>= 1) { if (t < s) s_red[t] += s_red[t + s]; __syncthreads(); }
    if (t == 0 && s_red[0] != 0.f) atomicAdd(e_pair, (double)s_red[0]);
}

// ---------------------------------------------------------------------------
// K5: energy = e_pair + coulomb_scale*e_lr + sum(atom_bias[species])
// ---------------------------------------------------------------------------
__global__ __launch_bounds__(256) void k_final(
    const int* __restrict__ species, const float* __restrict__ atom_bias,
    const float* __restrict__ coulomb_scale,
    const double* __restrict__ e_pair, const double* __restrict__ e_lr,
    float* __restrict__ out_energy)
{
    __shared__ float s_red[256];
    const int t = threadIdx.x;
    float acc = 0.f;
    for (int idx = t; idx < NATOMS; idx += 256) acc += atom_bias[species[idx]];
    s_red[t] = acc;
    __syncthreads();
    for (int s = 128; s > 0; s >>= 1) { if (t < s) s_red[t] += s_red[t + s]; __syncthreads(); }
    if (t == 0) {
        out_energy[0] = (float)(e_pair[0] + (double)coulomb_scale[0] * e_lr[0] + (double)s_red[0]);
    }
}

// ---------------------------------------------------------------------------
extern "C" void kernel_launch(void* const* d_in, const int* in_sizes, int n_in,
                              void* d_out, int out_size, void* d_ws, size_t ws_size,
                              hipStream_t stream) {
    const int*   species       = (const int*)d_in[0];
    const float* pos           = (const float*)d_in[1];
    const float* tq            = (const float*)d_in[2];
    const float* embed         = (const float*)d_in[3];
    const float* W1            = (const float*)d_in[4];
    const float* b1            = (const float*)d_in[5];
    const float* W2            = (const float*)d_in[6];
    const float* b2            = (const float*)d_in[7];
    const float* W3            = (const float*)d_in[8];
    const float* b3            = (const float*)d_in[9];
    const float* atom_bias     = (const float*)d_in[10];
    const float* cW1           = (const float*)d_in[11];
    const float* cb1           = (const float*)d_in[12];
    const float* cW2           = (const float*)d_in[13];
    const float* cb2           = (const float*)d_in[14];
    const float* cW3           = (const float*)d_in[15];
    const float* cb3           = (const float*)d_in[16];
    const float* charge_scale  = (const float*)d_in[17];
    const float* coulomb_scale = (const float*)d_in[18];
    const float* softening     = (const float*)d_in[19];

    char* ws = (char*)d_ws;
    double*   e_pair = (double*)(ws + 0);
    double*   e_lr   = (double*)(ws + 8);
    unsigned* pcount = (unsigned*)(ws + 16);
    float*    raw    = (float*)(ws + 32);        // 6144 B
    float*    W2t    = (float*)(ws + 8192);      // 16384 B
    float*    ctab   = (float*)(ws + 24576);     // 64*64*4 = 16384 B
    unsigned* plist  = (unsigned*)(ws + 49152);  // ~700 KB

    float* out     = (float*)d_out;
    float* charges = out + 1;   // output layout: [energy, charges[1536]]

    hipMemsetAsync(d_ws, 0, 32, stream);  // zero e_pair, e_lr, pcount

    k_prep<<<80, 256, 0, stream>>>(W1, b1, W2, embed, W2t, ctab);
    k_local<<<NATOMS, 256, 0, stream>>>(species, pos, tq, embed,
                                        cW1, cb1, cW2, cb2, cW3, cb3,
                                        charge_scale, raw, pcount, plist);
    k_charges<<<1, 256, 0, stream>>>(raw, tq, charges);
    k_lr<<<512, 256, 0, stream>>>(pos, charges, softening, e_lr);
    k_pair<<<1024, 256, 0, stream>>>(pos, W1, b2, W3, b3, W2t, ctab,
                                     pcount, plist, e_pair);
    k_final<<<1, 256, 0, stream>>>(species, atom_bias, coulomb_scale,
                                   e_pair, e_lr, out);
}

// Round 6
// 203.233 us; speedup vs baseline: 3.3503x; 1.0394x over previous
//
#include <hip/hip_runtime.h>
#include <math.h>

#define NATOMS 1536
#define NSPEC 8
#define HID 64
#define NCEN 32
#define CUTOFF_R 5.0f
#define PI_F 3.14159265358979323846f
#define NBR_CAP 1024   // max in-cutoff neighbors per atom (~560 worst case here)
#define PREP_BLOCKS 80

__device__ __forceinline__ float silu_f(float x) {
    return x / (1.f + __expf(-x));
}

// ---------------------------------------------------------------------------
// K1: blocks 0..1535: per-atom work (neighbor compaction -> basis -> charge
//     MLP -> pair-list append). Blocks 1536..1615: prep (W2 transpose +
//     species-combo table for k_pair's layer 1).
// ---------------------------------------------------------------------------
__global__ __launch_bounds__(256) void k_local(
    const int* __restrict__ species, const float* __restrict__ pos,
    const float* __restrict__ tq, const float* __restrict__ embed,
    const float* __restrict__ cW1, const float* __restrict__ cb1,
    const float* __restrict__ cW2, const float* __restrict__ cb2,
    const float* __restrict__ cW3, const float* __restrict__ cb3,
    const float* __restrict__ charge_scale,
    const float* __restrict__ W1, const float* __restrict__ b1,
    const float* __restrict__ W2,
    float* __restrict__ W2t, float* __restrict__ ctab,
    float* __restrict__ raw, unsigned int* __restrict__ pcount,
    unsigned int* __restrict__ plist)
{
    __shared__ float2 dc_l[NBR_CAP];            // 8 KB  (d, cut)
    __shared__ unsigned short spj_l[NBR_CAP];   // 2 KB  (species<<11 | j)
    __shared__ unsigned short pj_l[NBR_CAP];    // 2 KB
    __shared__ float s_part[8 * 256];           // 8 KB  (reused in phase 3)
    __shared__ float s_local[NSPEC * NCEN];     // 1 KB
    __shared__ float s_h[64];
    __shared__ unsigned n_cnt, p_cnt, s_base;

    const int t = threadIdx.x;

    // ---------------- prep blocks ----------------
    if (blockIdx.x >= NATOMS) {
        const int b = blockIdx.x - NATOMS;
        if (b < 16) {
            const int idx = b * 256 + t;
            const int o = idx >> 6, k = idx & 63;
            W2t[idx] = W2[k * HID + o];
        } else if (t < 64) {
            const int c = b - 16;             // combo = si*8+sj
            const int si2 = c >> 3, sj2 = c & 7;
            const int o = t;
            float acc = b1[o];
            #pragma unroll 4
            for (int k = 0; k < 32; k++) {
                const float a = embed[si2 * 32 + k];
                const float bb = embed[sj2 * 32 + k];
                acc += (a + bb) * W1[(32 + k) * HID + o];
                acc += (a * bb) * W1[(64 + k) * HID + o];
            }
            ctab[c * HID + o] = acc;
        }
        return;
    }

    const int i = blockIdx.x;
    const int lane = t & 63;
    if (t == 0) { n_cnt = 0u; p_cnt = 0u; }
    __syncthreads();

    const float xi = pos[3*i+0], yi = pos[3*i+1], zi = pos[3*i+2];
    const int si = species[i];

    // ---- phase 1: neighbor compaction ----
    #pragma unroll
    for (int j0 = 0; j0 < NATOMS; j0 += 256) {
        const int j = j0 + t;
        const float dx = xi - pos[3*j+0];
        const float dy = yi - pos[3*j+1];
        const float dz = zi - pos[3*j+2];
        const float d = sqrtf(dx*dx + dy*dy + dz*dz + 1e-12f);
        const bool within = (d < CUTOFF_R) && (j != i);
        const unsigned long long m = __ballot((int)within);
        if (within) {
            const unsigned prefix = (unsigned)__popcll(m & ((1ull << lane) - 1ull));
            unsigned base = 0;
            if (prefix == 0) base = atomicAdd(&n_cnt, (unsigned)__popcll(m));
            base = (unsigned)__builtin_amdgcn_readfirstlane((int)base);
            const unsigned ofs = base + prefix;
            if (ofs < NBR_CAP) {
                dc_l[ofs] = make_float2(d, 0.5f * (__cosf((PI_F / CUTOFF_R) * d) + 1.f));
                spj_l[ofs] = (unsigned short)((species[j] << 11) | j);
            }
        }
    }
    __syncthreads();
    const unsigned cnt = (n_cnt < NBR_CAP) ? n_cnt : NBR_CAP;

    // ---- phase 1b: pair list (j > i) ----
    for (unsigned n0 = 0; n0 < cnt; n0 += 256) {
        const unsigned n = n0 + (unsigned)t;
        bool app = false; unsigned short w = 0;
        if (n < cnt) { w = spj_l[n]; app = ((int)(w & 2047u) > i); }
        const unsigned long long m = __ballot((int)app);
        if (app) {
            const unsigned prefix = (unsigned)__popcll(m & ((1ull << lane) - 1ull));
            unsigned base = 0;
            if (prefix == 0) base = atomicAdd(&p_cnt, (unsigned)__popcll(m));
            base = (unsigned)__builtin_amdgcn_readfirstlane((int)base);
            pj_l[base + prefix] = w;
        }
    }
    __syncthreads();
    if (t == 0) s_base = atomicAdd(pcount, p_cnt);
    __syncthreads();
    {
        const unsigned pc = p_cnt, base = s_base;
        for (unsigned idx = (unsigned)t; idx < pc; idx += 256) {
            const unsigned w = pj_l[idx];
            const unsigned jj = w & 2047u, spj = w >> 11;
            // packed: combo(6) | i(11) | j(11)
            plist[base + idx] = (((unsigned)si * 8u + spj) << 22)
                              | ((unsigned)i << 11) | jj;
        }
    }

    // ---- phase 2: register-bucket basis accumulation ----
    {
        const int k = t & 31, g = t >> 5;
        const float ck = (float)k * (CUTOFF_R / 31.f);
        float f0=0.f,f1=0.f,f2=0.f,f3=0.f,f4=0.f,f5=0.f,f6=0.f,f7=0.f;
        for (unsigned n = (unsigned)g; n < cnt; n += 8) {
            const float2 dc = dc_l[n];
            const float diff = dc.x - ck;
            const float v = __expf(-4.f * diff * diff) * dc.y;
            const int sp = (int)(spj_l[n] >> 11);
            f0 += (sp == 0) ? v : 0.f;
            f1 += (sp == 1) ? v : 0.f;
            f2 += (sp == 2) ? v : 0.f;
            f3 += (sp == 3) ? v : 0.f;
            f4 += (sp == 4) ? v : 0.f;
            f5 += (sp == 5) ? v : 0.f;
            f6 += (sp == 6) ? v : 0.f;
            f7 += (sp == 7) ? v : 0.f;
        }
        float* sp_g = &s_part[g * 256 + k];
        sp_g[0*32] = f0; sp_g[1*32] = f1; sp_g[2*32] = f2; sp_g[3*32] = f3;
        sp_g[4*32] = f4; sp_g[5*32] = f5; sp_g[6*32] = f6; sp_g[7*32] = f7;
    }
    __syncthreads();
    {
        float acc = 0.f;
        #pragma unroll
        for (int g2 = 0; g2 < 8; g2++) acc += s_part[g2 * 256 + t];
        s_local[t] = acc;
    }
    __syncthreads();

    // ---- phase 3: charge MLP x = [s_local(256), embed[si](32), Q(1)] ----
    const float Q = tq[0];
    {   // layer 1: 289 -> 64, partials
        const int g3 = t >> 6, o = t & 63;
        const int k0 = g3 * 73;
        const int k1 = (g3 == 3) ? 289 : (k0 + 73);
        float acc = 0.f;
        #pragma unroll 4
        for (int k = k0; k < k1; k++) {
            float xv;
            if (k < 256)      xv = s_local[k];
            else if (k < 288) xv = embed[si * 32 + (k - 256)];
            else              xv = Q;
            acc += xv * cW1[k * 64 + o];
        }
        s_part[g3 * 64 + o] = acc;
    }
    __syncthreads();
    if (t < 64) {
        const float a = cb1[t] + s_part[t] + s_part[64 + t]
                      + s_part[128 + t] + s_part[192 + t];
        s_h[t] = silu_f(a);
    }
    __syncthreads();
    {   // layer 2: 64 -> 64, partials
        const int g3 = t >> 6, o = t & 63;
        float acc = 0.f;
        #pragma unroll
        for (int kk = 0; kk < 16; kk++) {
            const int k = g3 * 16 + kk;
            acc += s_h[k] * cW2[k * 64 + o];
        }
        s_part[g3 * 64 + o] = acc;
    }
    __syncthreads();
    if (t < 64) {   // layer 3: 64 -> 1
        const float a = cb2[t] + s_part[t] + s_part[64 + t]
                      + s_part[128 + t] + s_part[192 + t];
        float v = silu_f(a) * cW3[t];
        #pragma unroll
        for (int off = 32; off > 0; off >>= 1) v += __shfl_down(v, off);
        if (t == 0) raw[i] = (v + cb3[0]) * charge_scale[0];
    }
}

// ---------------------------------------------------------------------------
// K2: charges = raw - mean(raw) + Q/N   (single block)
// ---------------------------------------------------------------------------
__global__ __launch_bounds__(256) void k_charges(
    const float* __restrict__ raw, const float* __restrict__ tq,
    float* __restrict__ charges)
{
    __shared__ float s_red[256];
    const int t = threadIdx.x;
    float acc = 0.f;
    for (int idx = t; idx < NATOMS; idx += 256) acc += raw[idx];
    s_red[t] = acc;
    __syncthreads();
    for (int s = 128; s > 0; s >>= 1) { if (t < s) s_red[t] += s_red[t + s]; __syncthreads(); }
    const float mean = s_red[0] / (float)NATOMS;
    const float add = tq[0] / (float)NATOMS;
    for (int idx = t; idx < NATOMS; idx += 256) charges[idx] = raw[idx] - mean + add;
}

// ---------------------------------------------------------------------------
// K3: long-range Coulomb, persistent blocks
// ---------------------------------------------------------------------------
__global__ __launch_bounds__(256) void k_lr(
    const float* __restrict__ pos, const float* __restrict__ charges,
    const float* __restrict__ softening, double* __restrict__ e_lr)
{
    __shared__ float s_red[256];
    const int t = threadIdx.x;
    const float sr = softening[0];
    const float sp = ((sr > 20.f) ? sr : log1pf(__expf(sr))) + 0.001f;
    const float sp2 = sp * sp;
    float acc = 0.f;
    for (int i = blockIdx.x; i < NATOMS; i += gridDim.x) {
        const float xi = pos[3*i+0], yi = pos[3*i+1], zi = pos[3*i+2];
        const float qi = charges[i];
        for (int j = i + 1 + t; j < NATOMS; j += 256) {
            const float dx = xi - pos[3*j+0];
            const float dy = yi - pos[3*j+1];
            const float dz = zi - pos[3*j+2];
            const float d2 = dx*dx + dy*dy + dz*dz + 1e-12f;
            acc += qi * charges[j] * rsqrtf(d2 + sp2);
        }
    }
    s_red[t] = acc;
    __syncthreads();
    for (int s = 128; s > 0; s >>= 1) { if (t < s) s_red[t] += s_red[t + s]; __syncthreads(); }
    if (t == 0 && s_red[0] != 0.f) atomicAdd(e_lr, (double)s_red[0]);
}

// ---------------------------------------------------------------------------
// K4: dense pair MLP. __launch_bounds__(256,4) -> 128-VGPR budget so a1[64]
// stays in VGPRs (round-5's 52-VGPR allocation spilled it to AGPRs: +8K cyc
// of v_accvgpr copies per wave-iter). Layer-1 embed part folded into
// ctab[combo]; weights streamed on the scalar path; layers 2+3 fused.
// ---------------------------------------------------------------------------
__global__ __launch_bounds__(256, 4) void k_pair(
    const float* __restrict__ pos,
    const float* __restrict__ W1,
    const float* __restrict__ b2,
    const float* __restrict__ W3, const float* __restrict__ b3,
    const float* __restrict__ W2t, const float* __restrict__ ctab,
    const unsigned int* __restrict__ pcount, const unsigned int* __restrict__ plist,
    double* __restrict__ e_pair)
{
    __shared__ float s_red[256];
    const int t = threadIdx.x;

    const float4* __restrict__ w1q = (const float4*)W1;   // rows m=0..31, [m][o4]
    const float4* __restrict__ w2q = (const float4*)W2t;  // [o][k4]
    const float4* __restrict__ ct4 = (const float4*)ctab; // [combo][o4]
    const float b3v = b3[0];
    const unsigned cnt = *pcount;
    float esum = 0.f;

    for (unsigned p = blockIdx.x * 256u + (unsigned)t; p < cnt; p += gridDim.x * 256u) {
        const unsigned pk = plist[p];
        const int combo = (int)(pk >> 22);
        const int i = (int)((pk >> 11) & 2047u);
        const int j = (int)(pk & 2047u);
        const float dx = pos[3*i+0] - pos[3*j+0];
        const float dy = pos[3*i+1] - pos[3*j+1];
        const float dz = pos[3*i+2] - pos[3*j+2];
        const float d = sqrtf(dx*dx + dy*dy + dz*dz + 1e-12f);
        const float cut = 0.5f * (__cosf((PI_F / CUTOFF_R) * d) + 1.f);

        // a1 init = combo table row (per-lane vector loads, L1-resident)
        float a1[HID];
        #pragma unroll
        for (int o4 = 0; o4 < 16; o4++) {
            const float4 c = ct4[combo * 16 + o4];
            a1[4*o4+0] = c.x; a1[4*o4+1] = c.y; a1[4*o4+2] = c.z; a1[4*o4+3] = c.w;
        }

        // RBF rows m = 0..31 (weights on scalar path)
        #pragma unroll 2
        for (int m = 0; m < NCEN; m++) {
            const float diff = d - (float)m * (CUTOFF_R / 31.f);
            const float f = __expf(-4.f * diff * diff);
            #pragma unroll
            for (int o4 = 0; o4 < 16; o4++) {
                const float4 w = w1q[m * 16 + o4];
                a1[4*o4+0] += f * w.x; a1[4*o4+1] += f * w.y;
                a1[4*o4+2] += f * w.z; a1[4*o4+3] += f * w.w;
            }
        }
        #pragma unroll
        for (int o = 0; o < HID; o++) a1[o] = silu_f(a1[o]);

        // layers 2+3 fused (one scalar a2 live at a time)
        float e = b3v;
        #pragma unroll 2
        for (int o = 0; o < HID; o++) {
            float acc = b2[o];
            #pragma unroll
            for (int k4 = 0; k4 < 16; k4++) {
                const float4 w = w2q[o * 16 + k4];
                acc += a1[4*k4+0]*w.x + a1[4*k4+1]*w.y
                     + a1[4*k4+2]*w.z + a1[4*k4+3]*w.w;
            }
            e += silu_f(acc) * W3[o];
        }
        esum += e * cut;
    }

    s_red[t] = esum;
    __syncthreads();
    for (int s = 128; s > 0; s >>= 1) { if (t < s) s_red[t] += s_red[t + s]; __syncthreads(); }
    if (t == 0 && s_red[0] != 0.f) atomicAdd(e_pair, (double)s_red[0]);
}

// ---------------------------------------------------------------------------
// K5: energy = e_pair + coulomb_scale*e_lr + sum(atom_bias[species])
// ---------------------------------------------------------------------------
__global__ __launch_bounds__(256) void k_final(
    const int* __restrict__ species, const float* __restrict__ atom_bias,
    const float* __restrict__ coulomb_scale,
    const double* __restrict__ e_pair, const double* __restrict__ e_lr,
    float* __restrict__ out_energy)
{
    __shared__ float s_red[256];
    const int t = threadIdx.x;
    float acc = 0.f;
    for (int idx = t; idx < NATOMS; idx += 256) acc += atom_bias[species[idx]];
    s_red[t] = acc;
    __syncthreads();
    for (int s = 128; s > 0; s >>= 1) { if (t < s) s_red[t] += s_red[t + s]; __syncthreads(); }
    if (t == 0) {
        out_energy[0] = (float)(e_pair[0] + (double)coulomb_scale[0] * e_lr[0] + (double)s_red[0]);
    }
}

// ---------------------------------------------------------------------------
extern "C" void kernel_launch(void* const* d_in, const int* in_sizes, int n_in,
                              void* d_out, int out_size, void* d_ws, size_t ws_size,
                              hipStream_t stream) {
    const int*   species       = (const int*)d_in[0];
    const float* pos           = (const float*)d_in[1];
    const float* tq            = (const float*)d_in[2];
    const float* embed         = (const float*)d_in[3];
    const float* W1            = (const float*)d_in[4];
    const float* b1            = (const float*)d_in[5];
    const float* W2            = (const float*)d_in[6];
    const float* b2            = (const float*)d_in[7];
    const float* W3            = (const float*)d_in[8];
    const float* b3            = (const float*)d_in[9];
    const float* atom_bias     = (const float*)d_in[10];
    const float* cW1           = (const float*)d_in[11];
    const float* cb1           = (const float*)d_in[12];
    const float* cW2           = (const float*)d_in[13];
    const float* cb2           = (const float*)d_in[14];
    const float* cW3           = (const float*)d_in[15];
    const float* cb3           = (const float*)d_in[16];
    const float* charge_scale  = (const float*)d_in[17];
    const float* coulomb_scale = (const float*)d_in[18];
    const float* softening     = (const float*)d_in[19];

    char* ws = (char*)d_ws;
    double*   e_pair = (double*)(ws + 0);
    double*   e_lr   = (double*)(ws + 8);
    unsigned* pcount = (unsigned*)(ws + 16);
    float*    raw    = (float*)(ws + 32);        // 6144 B
    float*    W2t    = (float*)(ws + 8192);      // 16384 B
    float*    ctab   = (float*)(ws + 24576);     // 64*64*4 = 16384 B
    unsigned* plist  = (unsigned*)(ws + 49152);  // ~700 KB

    float* out     = (float*)d_out;
    float* charges = out + 1;   // output layout: [energy, charges[1536]]

    hipMemsetAsync(d_ws, 0, 32, stream);  // zero e_pair, e_lr, pcount

    k_local<<<NATOMS + PREP_BLOCKS, 256, 0, stream>>>(
        species, pos, tq, embed,
        cW1, cb1, cW2, cb2, cW3, cb3, charge_scale,
        W1, b1, W2, W2t, ctab,
        raw, pcount, plist);
    k_charges<<<1, 256, 0, stream>>>(raw, tq, charges);
    k_lr<<<512, 256, 0, stream>>>(pos, charges, softening, e_lr);
    k_pair<<<1024, 256, 0, stream>>>(pos, W1, b2, W3, b3, W2t, ctab,
                                     pcount, plist, e_pair);
    k_final<<<1, 256, 0, stream>>>(species, atom_bias, coulomb_scale,
                                   e_pair, e_lr, out);
}

// Round 7
// 179.435 us; speedup vs baseline: 3.7947x; 1.1326x over previous
//
#include <hip/hip_runtime.h>
#include <math.h>

#define NATOMS 1536
#define NSPEC 8
#define HID 64
#define NCEN 32
#define CUTOFF_R 5.0f
#define PI_F 3.14159265358979323846f
#define NBR_CAP 1024   // max in-cutoff neighbors per atom (~560 worst case here)
#define PREP_BLOCKS 65

typedef __attribute__((ext_vector_type(8))) short short8;   // 8 bf16 (4 VGPRs)
typedef __attribute__((ext_vector_type(4))) float float4v;  // MFMA C/D

__device__ __forceinline__ float silu_f(float x) {
    return x / (1.f + __expf(-x));
}

// f32 -> bf16 with round-to-nearest-even
__device__ __forceinline__ short f2bf(float x) {
    unsigned u = __float_as_uint(x);
    u += 0x7fffu + ((u >> 16) & 1u);
    return (short)(u >> 16);
}

// ---------------------------------------------------------------------------
// K1: blocks 0..1535: per-atom work. Blocks 1536..1600: prep:
//   b in [0,64):  ctab[c][o] = b1[o] + sum_k (ei+ej)W1[32+k][o] + (ei*ej)W1[64+k][o]
//   b == 64:      bw1 = W1[0:32] in bf16 MFMA B-frag order (4 N-tiles);
//                 bw2 = W2 in bf16 B-frag order (2 K-chunks x 4 N-tiles).
//   B-frag order: frag[f][lane][j] = W[k = chunk*32 + (lane>>4)*8 + j][n = tile*16 + (lane&15)]
// ---------------------------------------------------------------------------
__global__ __launch_bounds__(256) void k_local(
    const int* __restrict__ species, const float* __restrict__ pos,
    const float* __restrict__ tq, const float* __restrict__ embed,
    const float* __restrict__ cW1, const float* __restrict__ cb1,
    const float* __restrict__ cW2, const float* __restrict__ cb2,
    const float* __restrict__ cW3, const float* __restrict__ cb3,
    const float* __restrict__ charge_scale,
    const float* __restrict__ W1, const float* __restrict__ b1,
    const float* __restrict__ W2,
    float* __restrict__ ctab, short* __restrict__ bw1, short* __restrict__ bw2,
    float* __restrict__ raw, unsigned int* __restrict__ pcount,
    unsigned int* __restrict__ plist)
{
    __shared__ float2 dc_l[NBR_CAP];            // 8 KB  (d, cut)
    __shared__ unsigned short spj_l[NBR_CAP];   // 2 KB  (species<<11 | j)
    __shared__ unsigned short pj_l[NBR_CAP];    // 2 KB
    __shared__ float s_part[8 * 256];           // 8 KB  (reused in phase 3)
    __shared__ float s_local[NSPEC * NCEN];     // 1 KB
    __shared__ float s_h[64];
    __shared__ unsigned n_cnt, p_cnt, s_base;

    const int t = threadIdx.x;

    // ---------------- prep blocks ----------------
    if (blockIdx.x >= NATOMS) {
        const int b = blockIdx.x - NATOMS;
        if (b < 64) {
            if (t < 64) {
                const int c = b;                  // combo = si*8+sj
                const int si2 = c >> 3, sj2 = c & 7;
                const int o = t;
                float acc = b1[o];
                #pragma unroll 4
                for (int k = 0; k < 32; k++) {
                    const float a = embed[si2 * 32 + k];
                    const float bb = embed[sj2 * 32 + k];
                    acc += (a + bb) * W1[(32 + k) * HID + o];
                    acc += (a * bb) * W1[(64 + k) * HID + o];
                }
                ctab[c * HID + o] = acc;
            }
        } else {
            // bw1: 4 tiles * 64 lanes * 8 = 2048 elems
            for (int e = t; e < 2048; e += 256) {
                const int tile = e >> 9, L = (e >> 3) & 63, j = e & 7;
                const int k = (L >> 4) * 8 + j;
                const int n = tile * 16 + (L & 15);
                bw1[e] = f2bf(W1[k * HID + n]);
            }
            // bw2: 2 chunks * 4 tiles * 64 lanes * 8 = 4096 elems
            for (int e = t; e < 4096; e += 256) {
                const int ct = e >> 9, L = (e >> 3) & 63, j = e & 7;
                const int c = ct >> 2, tile = ct & 3;
                const int k = c * 32 + (L >> 4) * 8 + j;
                const int n = tile * 16 + (L & 15);
                bw2[e] = f2bf(W2[k * HID + n]);
            }
        }
        return;
    }

    const int i = blockIdx.x;
    const int lane = t & 63;
    if (t == 0) { n_cnt = 0u; p_cnt = 0u; }
    __syncthreads();

    const float xi = pos[3*i+0], yi = pos[3*i+1], zi = pos[3*i+2];
    const int si = species[i];

    // ---- phase 1: neighbor compaction ----
    #pragma unroll
    for (int j0 = 0; j0 < NATOMS; j0 += 256) {
        const int j = j0 + t;
        const float dx = xi - pos[3*j+0];
        const float dy = yi - pos[3*j+1];
        const float dz = zi - pos[3*j+2];
        const float d = sqrtf(dx*dx + dy*dy + dz*dz + 1e-12f);
        const bool within = (d < CUTOFF_R) && (j != i);
        const unsigned long long m = __ballot((int)within);
        if (within) {
            const unsigned prefix = (unsigned)__popcll(m & ((1ull << lane) - 1ull));
            unsigned base = 0;
            if (prefix == 0) base = atomicAdd(&n_cnt, (unsigned)__popcll(m));
            base = (unsigned)__builtin_amdgcn_readfirstlane((int)base);
            const unsigned ofs = base + prefix;
            if (ofs < NBR_CAP) {
                dc_l[ofs] = make_float2(d, 0.5f * (__cosf((PI_F / CUTOFF_R) * d) + 1.f));
                spj_l[ofs] = (unsigned short)((species[j] << 11) | j);
            }
        }
    }
    __syncthreads();
    const unsigned cnt = (n_cnt < NBR_CAP) ? n_cnt : NBR_CAP;

    // ---- phase 1b: pair list (j > i) ----
    for (unsigned n0 = 0; n0 < cnt; n0 += 256) {
        const unsigned n = n0 + (unsigned)t;
        bool app = false; unsigned short w = 0;
        if (n < cnt) { w = spj_l[n]; app = ((int)(w & 2047u) > i); }
        const unsigned long long m = __ballot((int)app);
        if (app) {
            const unsigned prefix = (unsigned)__popcll(m & ((1ull << lane) - 1ull));
            unsigned base = 0;
            if (prefix == 0) base = atomicAdd(&p_cnt, (unsigned)__popcll(m));
            base = (unsigned)__builtin_amdgcn_readfirstlane((int)base);
            pj_l[base + prefix] = w;
        }
    }
    __syncthreads();
    if (t == 0) s_base = atomicAdd(pcount, p_cnt);
    __syncthreads();
    {
        const unsigned pc = p_cnt, base = s_base;
        for (unsigned idx = (unsigned)t; idx < pc; idx += 256) {
            const unsigned w = pj_l[idx];
            const unsigned jj = w & 2047u, spj = w >> 11;
            // packed: combo(6) | i(11) | j(11)
            plist[base + idx] = (((unsigned)si * 8u + spj) << 22)
                              | ((unsigned)i << 11) | jj;
        }
    }

    // ---- phase 2: register-bucket basis accumulation ----
    {
        const int k = t & 31, g = t >> 5;
        const float ck = (float)k * (CUTOFF_R / 31.f);
        float f0=0.f,f1=0.f,f2=0.f,f3=0.f,f4=0.f,f5=0.f,f6=0.f,f7=0.f;
        for (unsigned n = (unsigned)g; n < cnt; n += 8) {
            const float2 dc = dc_l[n];
            const float diff = dc.x - ck;
            const float v = __expf(-4.f * diff * diff) * dc.y;
            const int sp = (int)(spj_l[n] >> 11);
            f0 += (sp == 0) ? v : 0.f;
            f1 += (sp == 1) ? v : 0.f;
            f2 += (sp == 2) ? v : 0.f;
            f3 += (sp == 3) ? v : 0.f;
            f4 += (sp == 4) ? v : 0.f;
            f5 += (sp == 5) ? v : 0.f;
            f6 += (sp == 6) ? v : 0.f;
            f7 += (sp == 7) ? v : 0.f;
        }
        float* sp_g = &s_part[g * 256 + k];
        sp_g[0*32] = f0; sp_g[1*32] = f1; sp_g[2*32] = f2; sp_g[3*32] = f3;
        sp_g[4*32] = f4; sp_g[5*32] = f5; sp_g[6*32] = f6; sp_g[7*32] = f7;
    }
    __syncthreads();
    {
        float acc = 0.f;
        #pragma unroll
        for (int g2 = 0; g2 < 8; g2++) acc += s_part[g2 * 256 + t];
        s_local[t] = acc;
    }
    __syncthreads();

    // ---- phase 3: charge MLP x = [s_local(256), embed[si](32), Q(1)] ----
    const float Q = tq[0];
    {   // layer 1: 289 -> 64, partials
        const int g3 = t >> 6, o = t & 63;
        const int k0 = g3 * 73;
        const int k1 = (g3 == 3) ? 289 : (k0 + 73);
        float acc = 0.f;
        #pragma unroll 4
        for (int k = k0; k < k1; k++) {
            float xv;
            if (k < 256)      xv = s_local[k];
            else if (k < 288) xv = embed[si * 32 + (k - 256)];
            else              xv = Q;
            acc += xv * cW1[k * 64 + o];
        }
        s_part[g3 * 64 + o] = acc;
    }
    __syncthreads();
    if (t < 64) {
        const float a = cb1[t] + s_part[t] + s_part[64 + t]
                      + s_part[128 + t] + s_part[192 + t];
        s_h[t] = silu_f(a);
    }
    __syncthreads();
    {   // layer 2: 64 -> 64, partials
        const int g3 = t >> 6, o = t & 63;
        float acc = 0.f;
        #pragma unroll
        for (int kk = 0; kk < 16; kk++) {
            const int k = g3 * 16 + kk;
            acc += s_h[k] * cW2[k * 64 + o];
        }
        s_part[g3 * 64 + o] = acc;
    }
    __syncthreads();
    if (t < 64) {   // layer 3: 64 -> 1
        const float a = cb2[t] + s_part[t] + s_part[64 + t]
                      + s_part[128 + t] + s_part[192 + t];
        float v = silu_f(a) * cW3[t];
        #pragma unroll
        for (int off = 32; off > 0; off >>= 1) v += __shfl_down(v, off);
        if (t == 0) raw[i] = (v + cb3[0]) * charge_scale[0];
    }
}

// ---------------------------------------------------------------------------
// K2: charges = raw - mean(raw) + Q/N   (single block)
// ---------------------------------------------------------------------------
__global__ __launch_bounds__(256) void k_charges(
    const float* __restrict__ raw, const float* __restrict__ tq,
    float* __restrict__ charges)
{
    __shared__ float s_red[256];
    const int t = threadIdx.x;
    float acc = 0.f;
    for (int idx = t; idx < NATOMS; idx += 256) acc += raw[idx];
    s_red[t] = acc;
    __syncthreads();
    for (int s = 128; s > 0; s >>= 1) { if (t < s) s_red[t] += s_red[t + s]; __syncthreads(); }
    const float mean = s_red[0] / (float)NATOMS;
    const float add = tq[0] / (float)NATOMS;
    for (int idx = t; idx < NATOMS; idx += 256) charges[idx] = raw[idx] - mean + add;
}

// ---------------------------------------------------------------------------
// K3: long-range Coulomb, persistent blocks
// ---------------------------------------------------------------------------
__global__ __launch_bounds__(256) void k_lr(
    const float* __restrict__ pos, const float* __restrict__ charges,
    const float* __restrict__ softening, double* __restrict__ e_lr)
{
    __shared__ float s_red[256];
    const int t = threadIdx.x;
    const float sr = softening[0];
    const float sp = ((sr > 20.f) ? sr : log1pf(__expf(sr))) + 0.001f;
    const float sp2 = sp * sp;
    float acc = 0.f;
    for (int i = blockIdx.x; i < NATOMS; i += gridDim.x) {
        const float xi = pos[3*i+0], yi = pos[3*i+1], zi = pos[3*i+2];
        const float qi = charges[i];
        for (int j = i + 1 + t; j < NATOMS; j += 256) {
            const float dx = xi - pos[3*j+0];
            const float dy = yi - pos[3*j+1];
            const float dz = zi - pos[3*j+2];
            const float d2 = dx*dx + dy*dy + dz*dz + 1e-12f;
            acc += qi * charges[j] * rsqrtf(d2 + sp2);
        }
    }
    s_red[t] = acc;
    __syncthreads();
    for (int s = 128; s > 0; s >>= 1) { if (t < s) s_red[t] += s_red[t + s]; __syncthreads(); }
    if (t == 0 && s_red[0] != 0.f) atomicAdd(e_lr, (double)s_red[0]);
}

// ---------------------------------------------------------------------------
// K4: pair MLP on the MATRIX pipe. 16 pairs per wave.
//  L1: A = rbf features (computed in A-frag layout: lane -> pair lane&15,
//      k = quad*8+j), B = bw1 (pre-packed), C init = ctab[combo] fp32.
//      4 MFMAs (K=32 exactly). silu -> LDS transpose (stride 66) -> A-frag.
//  L2: 2 K-chunks x 4 N-tiles = 8 MFMAs, C init = b2.
//  L3 fused in epilogue: esum += cut * sum_n silu(a2)*W3[n]  (+ b3*cut once).
// Verified layouts (guide §3): A[m=lane&15][k=quad*8+j]; C/D col=lane&15,
// row=quad*4+reg. MFMA reads AGPRs natively -> no accvgpr-copy tax.
// ---------------------------------------------------------------------------
__global__ __launch_bounds__(256, 4) void k_pair(
    const float* __restrict__ pos,
    const float* __restrict__ b2, const float* __restrict__ W3,
    const float* __restrict__ b3, const float* __restrict__ ctab,
    const short* __restrict__ bw1, const short* __restrict__ bw2,
    const unsigned int* __restrict__ pcount, const unsigned int* __restrict__ plist,
    double* __restrict__ e_pair)
{
    __shared__ float s_tp[4][16 * 66];   // per-wave transpose buffer
    __shared__ float s_red[256];
    const int t = threadIdx.x;
    const int lane = t & 63;
    const int wid = t >> 6;
    const int col = lane & 15;
    const int quad = lane >> 4;

    // loop-invariant weight fragments (preloaded once)
    const short8* __restrict__ bw1v = (const short8*)bw1;
    const short8* __restrict__ bw2v = (const short8*)bw2;
    short8 w1f[4], w2f[8];
    #pragma unroll
    for (int t4 = 0; t4 < 4; t4++) w1f[t4] = bw1v[t4 * 64 + lane];
    #pragma unroll
    for (int q8 = 0; q8 < 8; q8++) w2f[q8] = bw2v[q8 * 64 + lane];
    float b2l[4], w3l[4];
    #pragma unroll
    for (int t4 = 0; t4 < 4; t4++) { b2l[t4] = b2[t4*16+col]; w3l[t4] = W3[t4*16+col]; }
    const float b3v = b3[0];
    const unsigned cnt = *pcount;
    float* tb = &s_tp[wid][0];

    float esum = 0.f;
    const unsigned wstep = gridDim.x * 4u;
    for (unsigned w = blockIdx.x * 4u + (unsigned)wid; w * 16u < cnt; w += wstep) {
        unsigned p_idx = w * 16u + (unsigned)col;
        const bool valid = p_idx < cnt;
        if (!valid) p_idx = cnt - 1;
        const unsigned pk = plist[p_idx];
        const int combo = (int)(pk >> 22);
        const int i = (int)((pk >> 11) & 2047u);
        const int j = (int)(pk & 2047u);
        const float dx = pos[3*i+0] - pos[3*j+0];
        const float dy = pos[3*i+1] - pos[3*j+1];
        const float dz = pos[3*i+2] - pos[3*j+2];
        const float d = sqrtf(dx*dx + dy*dy + dz*dz + 1e-12f);
        const float cut = valid ? 0.5f * (__cosf((PI_F / CUTOFF_R) * d) + 1.f) : 0.f;
        if (lane < 16) esum += b3v * cut;   // b3 counted once per pair

        // A1 fragment: rbf features of pair (lane&15) at centers quad*8+j
        short8 a1f;
        #pragma unroll
        for (int jj = 0; jj < 8; jj++) {
            const float ck = (float)(quad * 8 + jj) * (CUTOFF_R / 31.f);
            const float diff = d - ck;
            a1f[jj] = f2bf(__expf(-4.f * diff * diff));
        }

        // broadcast combo/cut of the 4 row-pairs this lane accumulates
        int cmb[4]; float cutr[4];
        #pragma unroll
        for (int r = 0; r < 4; r++) {
            const int p = quad * 4 + r;
            cmb[r]  = __shfl(combo, p);
            cutr[r] = __shfl(cut, p);
        }

        // L1: C init from ctab, then 4 MFMAs
        float4v acc[4];
        #pragma unroll
        for (int t4 = 0; t4 < 4; t4++) {
            #pragma unroll
            for (int r = 0; r < 4; r++)
                acc[t4][r] = ctab[cmb[r] * HID + t4 * 16 + col];
        }
        #pragma unroll
        for (int t4 = 0; t4 < 4; t4++)
            acc[t4] = __builtin_amdgcn_mfma_f32_16x16x32_bf16(a1f, w1f[t4], acc[t4], 0, 0, 0);

        // silu -> LDS (D-layout write), read back in A-layout
        #pragma unroll
        for (int t4 = 0; t4 < 4; t4++) {
            #pragma unroll
            for (int r = 0; r < 4; r++)
                tb[(quad * 4 + r) * 66 + t4 * 16 + col] = silu_f(acc[t4][r]);
        }
        short8 a2f[2];
        #pragma unroll
        for (int c = 0; c < 2; c++) {
            #pragma unroll
            for (int jj = 0; jj < 8; jj++)
                a2f[c][jj] = f2bf(tb[col * 66 + c * 32 + quad * 8 + jj]);
        }

        // L2: C init = b2, 8 MFMAs
        float4v acc2[4];
        #pragma unroll
        for (int t4 = 0; t4 < 4; t4++) {
            acc2[t4][0] = b2l[t4]; acc2[t4][1] = b2l[t4];
            acc2[t4][2] = b2l[t4]; acc2[t4][3] = b2l[t4];
        }
        #pragma unroll
        for (int c = 0; c < 2; c++) {
            #pragma unroll
            for (int t4 = 0; t4 < 4; t4++)
                acc2[t4] = __builtin_amdgcn_mfma_f32_16x16x32_bf16(a2f[c], w2f[c*4+t4], acc2[t4], 0, 0, 0);
        }

        // L3 epilogue
        #pragma unroll
        for (int r = 0; r < 4; r++) {
            float part = 0.f;
            #pragma unroll
            for (int t4 = 0; t4 < 4; t4++) part += silu_f(acc2[t4][r]) * w3l[t4];
            esum += part * cutr[r];
        }
    }

    s_red[t] = esum;
    __syncthreads();
    for (int s = 128; s > 0; s >>= 1) { if (t < s) s_red[t] += s_red[t + s]; __syncthreads(); }
    if (t == 0 && s_red[0] != 0.f) atomicAdd(e_pair, (double)s_red[0]);
}

// ---------------------------------------------------------------------------
// K5: energy = e_pair + coulomb_scale*e_lr + sum(atom_bias[species])
// ---------------------------------------------------------------------------
__global__ __launch_bounds__(256) void k_final(
    const int* __restrict__ species, const float* __restrict__ atom_bias,
    const float* __restrict__ coulomb_scale,
    const double* __restrict__ e_pair, const double* __restrict__ e_lr,
    float* __restrict__ out_energy)
{
    __shared__ float s_red[256];
    const int t = threadIdx.x;
    float acc = 0.f;
    for (int idx = t; idx < NATOMS; idx += 256) acc += atom_bias[species[idx]];
    s_red[t] = acc;
    __syncthreads();
    for (int s = 128; s > 0; s >>= 1) { if (t < s) s_red[t] += s_red[t + s]; __syncthreads(); }
    if (t == 0) {
        out_energy[0] = (float)(e_pair[0] + (double)coulomb_scale[0] * e_lr[0] + (double)s_red[0]);
    }
}

// ---------------------------------------------------------------------------
extern "C" void kernel_launch(void* const* d_in, const int* in_sizes, int n_in,
                              void* d_out, int out_size, void* d_ws, size_t ws_size,
                              hipStream_t stream) {
    const int*   species       = (const int*)d_in[0];
    const float* pos           = (const float*)d_in[1];
    const float* tq            = (const float*)d_in[2];
    const float* embed         = (const float*)d_in[3];
    const float* W1            = (const float*)d_in[4];
    const float* b1            = (const float*)d_in[5];
    const float* W2            = (const float*)d_in[6];
    const float* b2            = (const float*)d_in[7];
    const float* W3            = (const float*)d_in[8];
    const float* b3            = (const float*)d_in[9];
    const float* atom_bias     = (const float*)d_in[10];
    const float* cW1           = (const float*)d_in[11];
    const float* cb1           = (const float*)d_in[12];
    const float* cW2           = (const float*)d_in[13];
    const float* cb2           = (const float*)d_in[14];
    const float* cW3           = (const float*)d_in[15];
    const float* cb3           = (const float*)d_in[16];
    const float* charge_scale  = (const float*)d_in[17];
    const float* coulomb_scale = (const float*)d_in[18];
    const float* softening     = (const float*)d_in[19];

    char* ws = (char*)d_ws;
    double*   e_pair = (double*)(ws + 0);
    double*   e_lr   = (double*)(ws + 8);
    unsigned* pcount = (unsigned*)(ws + 16);
    float*    raw    = (float*)(ws + 32);        // 6144 B
    float*    ctab   = (float*)(ws + 8192);      // 16384 B
    short*    bw1    = (short*)(ws + 24576);     // 4096 B
    short*    bw2    = (short*)(ws + 28672);     // 8192 B
    unsigned* plist  = (unsigned*)(ws + 40960);  // ~700 KB

    float* out     = (float*)d_out;
    float* charges = out + 1;   // output layout: [energy, charges[1536]]

    hipMemsetAsync(d_ws, 0, 32, stream);  // zero e_pair, e_lr, pcount

    k_local<<<NATOMS + PREP_BLOCKS, 256, 0, stream>>>(
        species, pos, tq, embed,
        cW1, cb1, cW2, cb2, cW3, cb3, charge_scale,
        W1, b1, W2, ctab, bw1, bw2,
        raw, pcount, plist);
    k_charges<<<1, 256, 0, stream>>>(raw, tq, charges);
    k_lr<<<512, 256, 0, stream>>>(pos, charges, softening, e_lr);
    k_pair<<<1024, 256, 0, stream>>>(pos, b2, W3, b3, ctab, bw1, bw2,
                                     pcount, plist, e_pair);
    k_final<<<1, 256, 0, stream>>>(species, atom_bias, coulomb_scale,
                                   e_pair, e_lr, out);
}